// Round 1
// baseline (891.143 us; speedup 1.0000x reference)
//
#include <hip/hip_runtime.h>
#include <hip/hip_bf16.h>

// Problem constants
#define HWSZ   262144   // 512*512
#define IMG    512
#define NBATCH 4
#define NBANDS 8

// ---------------------------------------------------------------------------
// Reduction helper: wave-level shuffle reduce + one double atomic per wave.
__device__ __forceinline__ void waveReduceAtomicAdd(double v, double* target) {
    for (int off = 32; off > 0; off >>= 1) v += __shfl_down(v, off, 64);
    if ((threadIdx.x & 63) == 0) atomicAdd(target, v);
}

// ---------------------------------------------------------------------------
// Pan smoothing (edge-pad 41x41 Gaussian, rank-1 factored), horizontal pass.
// grid: (2, 512, B), block 256.  out tmpH (B,512,512)
__global__ __launch_bounds__(256) void k_pan_h(const float* __restrict__ inp,
                                               const float* __restrict__ mtf,
                                               float* __restrict__ tmpH) {
    __shared__ float seg[296];
    __shared__ float vrow[41];
    const int tid = threadIdx.x;
    const int b = blockIdx.z, r = blockIdx.y, c0 = blockIdx.x * 256;
    if (tid < 41) vrow[tid] = mtf[20 * 41 + tid] / sqrtf(mtf[20 * 41 + 20]);
    const float* pan = inp + ((long)b * 9 + 8) * HWSZ + (long)r * IMG;
    for (int e = tid; e < 296; e += 256) {
        int c = c0 - 20 + e;
        c = min(max(c, 0), IMG - 1);
        seg[e] = pan[c];
    }
    __syncthreads();
    float s = 0.f;
#pragma unroll
    for (int j = 0; j < 41; ++j) s += vrow[j] * seg[tid + j];
    tmpH[(long)b * HWSZ + (long)r * IMG + c0 + tid] = s;
}

// Vertical pass: panf(b,r,c) = sum_i u_i * tmpH(b, clamp(r-20+i), c)
__global__ __launch_bounds__(256) void k_pan_v(const float* __restrict__ tmpH,
                                               const float* __restrict__ mtf,
                                               float* __restrict__ panf) {
    __shared__ float ucol[41];
    const int tid = threadIdx.x;
    const int b = blockIdx.z, r = blockIdx.y, c = blockIdx.x * 256 + tid;
    if (tid < 41) ucol[tid] = mtf[tid * 41 + 20] / sqrtf(mtf[20 * 41 + 20]);
    __syncthreads();
    const float* base = tmpH + (long)b * HWSZ;
    float s = 0.f;
#pragma unroll
    for (int i = 0; i < 41; ++i) {
        int rr = min(max(r - 20 + i, 0), IMG - 1);
        s += ucol[i] * base[(long)rr * IMG + c];
    }
    panf[(long)b * HWSZ + (long)r * IMG + c] = s;
}

// ---------------------------------------------------------------------------
// da field for a single-channel (B,1,H,W) input: da = x - boxsum(x)/n
// window [p-W+1, p+W], zero padding. grid (16,16,B), block 256, 32x32 tiles.
template <int W>
__global__ __launch_bounds__(256) void k_da(const float* __restrict__ in,
                                            long inBatchStride,
                                            float* __restrict__ out) {
    constexpr int TS = 32, WIN = 2 * W, NN = 4 * W * W, RE = TS + WIN - 1;
    constexpr int SR = RE;   // odd (47 or 35) -> conflict-free columns
    constexpr int ST = 33;
    __shared__ float RAW[RE * SR];
    __shared__ float T[RE * ST];
    const int tid = threadIdx.x;
    const int tr0 = blockIdx.y * TS, tc0 = blockIdx.x * TS;
    const float* src = in + (long)blockIdx.z * inBatchStride;
    for (int e = tid; e < RE * RE; e += 256) {
        int r = e / RE, c = e % RE;
        int gr = tr0 - (W - 1) + r, gc = tc0 - (W - 1) + c;
        float v = 0.f;
        if (gr >= 0 && gr < IMG && gc >= 0 && gc < IMG) v = src[(long)gr * IMG + gc];
        RAW[r * SR + c] = v;
    }
    __syncthreads();
    for (int e = tid; e < RE * TS; e += 256) {
        int r = e >> 5, j = e & 31;
        float s = 0.f;
#pragma unroll
        for (int k = 0; k < WIN; ++k) s += RAW[r * SR + j + k];
        T[r * ST + j] = s;
    }
    __syncthreads();
    float* dst = out + (long)blockIdx.z * HWSZ;
    for (int e = tid; e < TS * TS; e += 256) {
        int pr = e >> 5, pc = e & 31;
        float s = 0.f;
#pragma unroll
        for (int k = 0; k < WIN; ++k) s += T[(pr + k) * ST + pc];
        float da = RAW[(pr + W - 1) * SR + (pc + W - 1)] - s * (1.0f / NN);
        dst[(long)(tr0 + pr) * IMG + tc0 + pc] = da;
    }
}

// s = boxsum(in^2), same window/padding. in/out (B,H,W), batch stride HWSZ.
template <int W>
__global__ __launch_bounds__(256) void k_sq(const float* __restrict__ in,
                                            float* __restrict__ out) {
    constexpr int TS = 32, WIN = 2 * W, RE = TS + WIN - 1;
    constexpr int SR = RE, ST = 33;
    __shared__ float RAW[RE * SR];
    __shared__ float T[RE * ST];
    const int tid = threadIdx.x;
    const int tr0 = blockIdx.y * TS, tc0 = blockIdx.x * TS;
    const float* src = in + (long)blockIdx.z * HWSZ;
    for (int e = tid; e < RE * RE; e += 256) {
        int r = e / RE, c = e % RE;
        int gr = tr0 - (W - 1) + r, gc = tc0 - (W - 1) + c;
        float v = 0.f;
        if (gr >= 0 && gr < IMG && gc >= 0 && gc < IMG) v = src[(long)gr * IMG + gc];
        RAW[r * SR + c] = v;
    }
    __syncthreads();
    for (int e = tid; e < RE * TS; e += 256) {
        int r = e >> 5, j = e & 31;
        float s = 0.f;
#pragma unroll
        for (int k = 0; k < WIN; ++k) {
            float v = RAW[r * SR + j + k];
            s += v * v;
        }
        T[r * ST + j] = s;
    }
    __syncthreads();
    float* dst = out + (long)blockIdx.z * HWSZ;
    for (int e = tid; e < TS * TS; e += 256) {
        int pr = e >> 5, pc = e & 31;
        float s = 0.f;
#pragma unroll
        for (int k = 0; k < WIN; ++k) s += T[(pr + k) * ST + pc];
        dst[(long)(tr0 + pr) * IMG + tc0 + pc] = s;
    }
}

// ---------------------------------------------------------------------------
// Strided MTF conv of outputs (zero pad), horizontal: only strided cols 2::4.
// grid (512, 32), block 128. tmpS (B*8, 512, 128)
__global__ __launch_bounds__(128) void k_spec_h(const float* __restrict__ outputs,
                                                const float* __restrict__ mtf,
                                                float* __restrict__ tmpS) {
    __shared__ float vrow[41];
    const int z = blockIdx.y, r = blockIdx.x, cs = threadIdx.x;
    const int band = z & 7;
    if (threadIdx.x < 41)
        vrow[threadIdx.x] = mtf[band * 1681 + 20 * 41 + threadIdx.x] /
                            sqrtf(mtf[band * 1681 + 20 * 41 + 20]);
    __syncthreads();
    const float* src = outputs + (long)z * HWSZ + (long)r * IMG;
    float s = 0.f;
    const int cbase = 2 + 4 * cs - 20;
#pragma unroll
    for (int j = 0; j < 41; ++j) {
        int c = cbase + j;
        if (c >= 0 && c < IMG) s += vrow[j] * src[c];
    }
    tmpS[((long)z * IMG + r) * 128 + cs] = s;
}

// Vertical + L_spec accumulation: acc[0] += |x*m - y*m|, acc[1] += m.
// grid 2048, block 256 (one thread per strided output point).
__global__ __launch_bounds__(256) void k_spec_v(const float* __restrict__ tmpS,
                                                const float* __restrict__ labels,
                                                const float* __restrict__ spec,
                                                const float* __restrict__ mtf,
                                                double* __restrict__ acc) {
    const int idx = blockIdx.x * 256 + threadIdx.x;   // < 4*8*128*128
    const int cs = idx & 127, rs = (idx >> 7) & 127, z = idx >> 14;
    const int b = z >> 3, band = z & 7;
    __shared__ float ucol[41];
    if (threadIdx.x < 41)
        ucol[threadIdx.x] = mtf[band * 1681 + threadIdx.x * 41 + 20] /
                            sqrtf(mtf[band * 1681 + 20 * 41 + 20]);
    __syncthreads();
    const float* col = tmpS + (long)z * IMG * 128 + cs;
    float x = 0.f;
    const int rbase = 2 + 4 * rs - 20;
#pragma unroll
    for (int i = 0; i < 41; ++i) {
        int r = rbase + i;
        if (r >= 0 && r < IMG) x += ucol[i] * col[(long)r * 128];
    }
    const int gr = 2 + 4 * rs, gc = 2 + 4 * cs;
    float m = spec[(long)band * HWSZ + (long)gr * IMG + gc];
    float y = labels[((long)b * 9 + band) * HWSZ + (long)gr * IMG + gc];
    float t = fabsf(x * m - y * m);
    waveReduceAtomicAdd((double)t, acc + 0);
    waveReduceAtomicAdd((double)m, acc + 1);
}

// ---------------------------------------------------------------------------
// Fused per-tile xcorr: raw field supplies the "in-tile" da; dS/sSS are the
// precomputed shared (single-channel) fields. Returns r = xcorr per output.
// Output tile 32x32, block 256 (4 outputs/thread).
template <int W>
__device__ __forceinline__ void xcorr_tile(const float* __restrict__ raw,
                                           const float* __restrict__ dS,
                                           const float* __restrict__ sSS,
                                           float* lds, int tr0, int tc0,
                                           int tid, float rOut[4]) {
    constexpr int TS = 32, WIN = 2 * W, NN = 4 * W * W;
    constexpr int QE = TS + 2 * W - 1;        // 47 / 35
    constexpr int AE = TS + 4 * W - 2;        // 62 / 38
    constexpr int SA = AE | 1;                // odd stride
    constexpr int SQ = QE;                    // odd
    constexpr int ST2 = 33;
    float* RAW = lds;                         // AE x SA
    float* T   = RAW + AE * SA;               // AE x SQ (also T2: QE x ST2)
    float* DR  = T + AE * SQ;                 // QE x SQ
    float* DSb = DR + QE * SQ;                // QE x SQ

    for (int e = tid; e < AE * AE; e += 256) {
        int r = e / AE, c = e % AE;
        int gr = tr0 - (2 * W - 2) + r, gc = tc0 - (2 * W - 2) + c;
        float v = 0.f;
        if (gr >= 0 && gr < IMG && gc >= 0 && gc < IMG) v = raw[(long)gr * IMG + gc];
        RAW[r * SA + c] = v;
    }
    for (int e = tid; e < QE * QE; e += 256) {
        int r = e / QE, c = e % QE;
        int gr = tr0 - (W - 1) + r, gc = tc0 - (W - 1) + c;
        float v = 0.f;
        if (gr >= 0 && gr < IMG && gc >= 0 && gc < IMG) v = dS[(long)gr * IMG + gc];
        DSb[r * SQ + c] = v;
    }
    __syncthreads();

    {   // horizontal sliding window sums: T(r, j) = sum_k RAW(r, j+k)
        constexpr int CH = (W == 8) ? 4 : 6;
        constexpr int LEN = (QE + CH - 1) / CH;
        const int r = tid / CH, ch = tid % CH;
        if (r < AE) {
            const int j0 = ch * LEN, j1 = min(j0 + LEN, QE);
            if (j0 < QE) {
                float s = 0.f;
#pragma unroll
                for (int k = 0; k < WIN; ++k) s += RAW[r * SA + j0 + k];
                T[r * SQ + j0] = s;
                for (int j = j0 + 1; j < j1; ++j) {
                    s += RAW[r * SA + j + WIN - 1] - RAW[r * SA + j - 1];
                    T[r * SQ + j] = s;
                }
            }
        }
    }
    __syncthreads();
    {   // vertical sliding sums -> DR = raw - mean (0 outside image)
        constexpr int CH = (W == 8) ? 5 : 7;
        constexpr int LEN = (QE + CH - 1) / CH;
        const int c = tid / CH, ch = tid % CH;
        if (c < QE) {
            const int r0 = ch * LEN, r1 = min(r0 + LEN, QE);
            if (r0 < QE) {
                float s = 0.f;
#pragma unroll
                for (int k = 0; k < WIN; ++k) s += T[(r0 + k) * SQ + c];
                for (int r = r0; r < r1; ++r) {
                    if (r > r0) s += T[(r + WIN - 1) * SQ + c] - T[(r - 1) * SQ + c];
                    int gr = tr0 - (W - 1) + r, gc = tc0 - (W - 1) + c;
                    float d = 0.f;
                    if (gr >= 0 && gr < IMG && gc >= 0 && gc < IMG)
                        d = RAW[(r + W - 1) * SA + (c + W - 1)] - s * (1.0f / NN);
                    DR[r * SQ + c] = d;
                }
            }
        }
    }
    __syncthreads();

    float sAcc[2][4];
    for (int pass = 0; pass < 2; ++pass) {
        {   // product horizontal sliding sums -> T2
            constexpr int CH = (W == 8) ? 5 : 7;
            constexpr int LEN = (TS + CH - 1) / CH;
            const int r = tid / CH, ch = tid % CH;
            if (r < QE) {
                const int j0 = ch * LEN, j1 = min(j0 + LEN, TS);
                if (j0 < TS) {
                    float s = 0.f;
                    if (pass == 0) {
#pragma unroll
                        for (int k = 0; k < WIN; ++k)
                            s += DR[r * SQ + j0 + k] * DSb[r * SQ + j0 + k];
                        T[r * ST2 + j0] = s;
                        for (int j = j0 + 1; j < j1; ++j) {
                            s += DR[r * SQ + j + WIN - 1] * DSb[r * SQ + j + WIN - 1] -
                                 DR[r * SQ + j - 1] * DSb[r * SQ + j - 1];
                            T[r * ST2 + j] = s;
                        }
                    } else {
#pragma unroll
                        for (int k = 0; k < WIN; ++k) {
                            float v = DR[r * SQ + j0 + k];
                            s += v * v;
                        }
                        T[r * ST2 + j0] = s;
                        for (int j = j0 + 1; j < j1; ++j) {
                            float vn = DR[r * SQ + j + WIN - 1], vo = DR[r * SQ + j - 1];
                            s += vn * vn - vo * vo;
                            T[r * ST2 + j] = s;
                        }
                    }
                }
            }
        }
        __syncthreads();
        for (int i = 0; i < 4; ++i) {
            int e = tid + 256 * i;
            int pr = e >> 5, pc = e & 31;
            float s = 0.f;
#pragma unroll
            for (int k = 0; k < WIN; ++k) s += T[(pr + k) * ST2 + pc];
            sAcc[pass][i] = s;
        }
        __syncthreads();
    }
    for (int i = 0; i < 4; ++i) {
        int e = tid + 256 * i;
        int pr = e >> 5, pc = e & 31;
        float sss = sSS[(long)(tr0 + pr) * IMG + tc0 + pc];
        float den = sqrtf(fmaxf(sAcc[1][i] * sss, 0.f)) + 1e-20f;
        rOut[i] = sAcc[0][i] / den;
    }
}

// Fused main: thr (w=8 on [pan_f, ms]) + X (w=2 on [outputs, pan]) + Y reduce.
// grid (16,16,32), block 256, ~45KB LDS.
__global__ __launch_bounds__(256) void k_main(const float* __restrict__ inp,
                                              const float* __restrict__ outputs,
                                              const float* __restrict__ da_pan,
                                              const float* __restrict__ saa_pan,
                                              const float* __restrict__ db_pan,
                                              const float* __restrict__ sbb_pan,
                                              double* __restrict__ acc) {
    __shared__ float lds[11238];   // 62*63 + 62*47 + 2*47*47 floats = 44952 B
    const int tid = threadIdx.x;
    const int tr0 = blockIdx.y * 32, tc0 = blockIdx.x * 32;
    const int z = blockIdx.z, b = z >> 3, band = z & 7;
    float rT[4], rX[4];
    // thr = 1 - xcorr(pan_f, ms, 8): in-tile field = ms band of `inp`
    xcorr_tile<8>(inp + ((long)b * 9 + band) * HWSZ, da_pan + (long)b * HWSZ,
                  saa_pan + (long)b * HWSZ, lds, tr0, tc0, tid, rT);
    __syncthreads();
    // Xc = xcorr(outputs, pan, 2): in-tile field = outputs band
    xcorr_tile<2>(outputs + (long)z * HWSZ, db_pan + (long)b * HWSZ,
                  sbb_pan + (long)b * HWSZ, lds, tr0, tc0, tid, rX);
    double ysum = 0.0;
#pragma unroll
    for (int i = 0; i < 4; ++i) {
        float thr = 1.0f - rT[i];
        float X = 1.0f - fmaxf(rX[i], -1.0f);
        if (X > thr) ysum += (double)X;
    }
    waveReduceAtomicAdd(ysum, acc + 2);
}

__global__ void k_final(const double* __restrict__ acc, float* __restrict__ out) {
    double lspec = acc[0] / acc[1];
    double lstruct = acc[2] / (double)(NBATCH * NBANDS * HWSZ);
    out[0] = (float)(lspec + 0.25 * lstruct);
}

// ---------------------------------------------------------------------------
extern "C" void kernel_launch(void* const* d_in, const int* in_sizes, int n_in,
                              void* d_out, int out_size, void* d_ws, size_t ws_size,
                              hipStream_t stream) {
    const float* outputs = (const float*)d_in[0];   // (4,8,512,512)
    const float* labels  = (const float*)d_in[1];   // (4,9,512,512)
    const float* inp     = (const float*)d_in[2];   // (4,9,512,512)
    const float* mtf     = (const float*)d_in[3];   // (8,1,41,41)
    const float* spec    = (const float*)d_in[4];   // (1,8,512,512)
    float* out = (float*)d_out;

    char* ws = (char*)d_ws;
    double* acc    = (double*)ws;                   // 3 doubles
    float* panf    = (float*)(ws + 1024);           // 4 MB
    float* tmpH    = panf + (long)NBATCH * HWSZ;    // 4 MB
    float* da_pan  = tmpH + (long)NBATCH * HWSZ;    // 4 MB
    float* saa_pan = da_pan + (long)NBATCH * HWSZ;  // 4 MB
    float* db_pan  = saa_pan + (long)NBATCH * HWSZ; // 4 MB
    float* sbb_pan = db_pan + (long)NBATCH * HWSZ;  // 4 MB
    float* tmpS    = sbb_pan + (long)NBATCH * HWSZ; // 4*8*512*128 floats = 8 MB

    hipMemsetAsync(acc, 0, 3 * sizeof(double), stream);

    // pan_f = edge-pad 41x41 conv of inp's pan channel (rank-1 factored)
    k_pan_h<<<dim3(2, 512, NBATCH), 256, 0, stream>>>(inp, mtf, tmpH);
    k_pan_v<<<dim3(2, 512, NBATCH), 256, 0, stream>>>(tmpH, mtf, panf);

    // shared-side fields for thr (w=8 on pan_f) and X (w=2 on labels' pan)
    k_da<8><<<dim3(16, 16, NBATCH), 256, 0, stream>>>(panf, (long)HWSZ, da_pan);
    k_sq<8><<<dim3(16, 16, NBATCH), 256, 0, stream>>>(da_pan, saa_pan);
    k_da<2><<<dim3(16, 16, NBATCH), 256, 0, stream>>>(labels + (long)8 * HWSZ,
                                                      (long)9 * HWSZ, db_pan);
    k_sq<2><<<dim3(16, 16, NBATCH), 256, 0, stream>>>(db_pan, sbb_pan);

    // L_spec: strided MTF conv of outputs + masked L1 accumulation
    k_spec_h<<<dim3(512, 32), 128, 0, stream>>>(outputs, mtf, tmpS);
    k_spec_v<<<dim3(2048), 256, 0, stream>>>(tmpS, labels, spec, mtf, acc);

    // fused thr + X + Y-mean accumulation
    k_main<<<dim3(16, 16, 32), 256, 0, stream>>>(inp, outputs, da_pan, saa_pan,
                                                 db_pan, sbb_pan, acc);

    k_final<<<1, 1, 0, stream>>>(acc, out);
}

// Round 3
// 481.813 us; speedup vs baseline: 1.8496x; 1.8496x over previous
//
#include <hip/hip_runtime.h>
#include <hip/hip_bf16.h>

// Problem constants
#define HWSZ   262144   // 512*512
#define IMG    512
#define NBATCH 4
#define NBANDS 8

// ---------------------------------------------------------------------------
// Block-level reduction: wave shuffle + LDS + one double atomic per block.
__device__ __forceinline__ void blockReduceAtomicAdd(double v, double* target,
                                                     double* red) {
    for (int off = 32; off > 0; off >>= 1) v += __shfl_down(v, off, 64);
    const int wave = threadIdx.x >> 6, lane = threadIdx.x & 63;
    if (lane == 0) red[wave] = v;
    __syncthreads();
    if (threadIdx.x == 0) atomicAdd(target, red[0] + red[1] + red[2] + red[3]);
}

// ---------------------------------------------------------------------------
// Pan smoothing (edge-pad 41x41 Gaussian, rank-1 factored), horizontal pass.
__global__ __launch_bounds__(256) void k_pan_h(const float* __restrict__ inp,
                                               const float* __restrict__ mtf,
                                               float* __restrict__ tmpH) {
    __shared__ float seg[296];
    __shared__ float vrow[41];
    const int tid = threadIdx.x;
    const int b = blockIdx.z, r = blockIdx.y, c0 = blockIdx.x * 256;
    if (tid < 41) vrow[tid] = mtf[20 * 41 + tid] / sqrtf(mtf[20 * 41 + 20]);
    const float* pan = inp + ((long)b * 9 + 8) * HWSZ + (long)r * IMG;
    for (int e = tid; e < 296; e += 256) {
        int c = c0 - 20 + e;
        c = min(max(c, 0), IMG - 1);
        seg[e] = pan[c];
    }
    __syncthreads();
    float s = 0.f;
#pragma unroll
    for (int j = 0; j < 41; ++j) s += vrow[j] * seg[tid + j];
    tmpH[(long)b * HWSZ + (long)r * IMG + c0 + tid] = s;
}

__global__ __launch_bounds__(256) void k_pan_v(const float* __restrict__ tmpH,
                                               const float* __restrict__ mtf,
                                               float* __restrict__ panf) {
    __shared__ float ucol[41];
    const int tid = threadIdx.x;
    const int b = blockIdx.z, r = blockIdx.y, c = blockIdx.x * 256 + tid;
    if (tid < 41) ucol[tid] = mtf[tid * 41 + 20] / sqrtf(mtf[20 * 41 + 20]);
    __syncthreads();
    const float* base = tmpH + (long)b * HWSZ;
    float s = 0.f;
#pragma unroll
    for (int i = 0; i < 41; ++i) {
        int rr = min(max(r - 20 + i, 0), IMG - 1);
        s += ucol[i] * base[(long)rr * IMG + c];
    }
    panf[(long)b * HWSZ + (long)r * IMG + c] = s;
}

// ---------------------------------------------------------------------------
// Small-field (4-image) helpers, LDS tile based (cheap at this size).
template <int W>
__global__ __launch_bounds__(256) void k_da(const float* __restrict__ in,
                                            long inBatchStride,
                                            float* __restrict__ out) {
    constexpr int TS = 32, WIN = 2 * W, NN = 4 * W * W, RE = TS + WIN - 1;
    constexpr int SR = RE;
    constexpr int ST = 33;
    __shared__ float RAW[RE * SR];
    __shared__ float T[RE * ST];
    const int tid = threadIdx.x;
    const int tr0 = blockIdx.y * TS, tc0 = blockIdx.x * TS;
    const float* src = in + (long)blockIdx.z * inBatchStride;
    for (int e = tid; e < RE * RE; e += 256) {
        int r = e / RE, c = e % RE;
        int gr = tr0 - (W - 1) + r, gc = tc0 - (W - 1) + c;
        float v = 0.f;
        if (gr >= 0 && gr < IMG && gc >= 0 && gc < IMG) v = src[(long)gr * IMG + gc];
        RAW[r * SR + c] = v;
    }
    __syncthreads();
    for (int e = tid; e < RE * TS; e += 256) {
        int r = e >> 5, j = e & 31;
        float s = 0.f;
#pragma unroll
        for (int k = 0; k < WIN; ++k) s += RAW[r * SR + j + k];
        T[r * ST + j] = s;
    }
    __syncthreads();
    float* dst = out + (long)blockIdx.z * HWSZ;
    for (int e = tid; e < TS * TS; e += 256) {
        int pr = e >> 5, pc = e & 31;
        float s = 0.f;
#pragma unroll
        for (int k = 0; k < WIN; ++k) s += T[(pr + k) * ST + pc];
        float da = RAW[(pr + W - 1) * SR + (pc + W - 1)] - s * (1.0f / NN);
        dst[(long)(tr0 + pr) * IMG + tc0 + pc] = da;
    }
}

template <int W>
__global__ __launch_bounds__(256) void k_sq(const float* __restrict__ in,
                                            float* __restrict__ out) {
    constexpr int TS = 32, WIN = 2 * W, RE = TS + WIN - 1;
    constexpr int SR = RE, ST = 33;
    __shared__ float RAW[RE * SR];
    __shared__ float T[RE * ST];
    const int tid = threadIdx.x;
    const int tr0 = blockIdx.y * TS, tc0 = blockIdx.x * TS;
    const float* src = in + (long)blockIdx.z * HWSZ;
    for (int e = tid; e < RE * RE; e += 256) {
        int r = e / RE, c = e % RE;
        int gr = tr0 - (W - 1) + r, gc = tc0 - (W - 1) + c;
        float v = 0.f;
        if (gr >= 0 && gr < IMG && gc >= 0 && gc < IMG) v = src[(long)gr * IMG + gc];
        RAW[r * SR + c] = v;
    }
    __syncthreads();
    for (int e = tid; e < RE * TS; e += 256) {
        int r = e >> 5, j = e & 31;
        float s = 0.f;
#pragma unroll
        for (int k = 0; k < WIN; ++k) {
            float v = RAW[r * SR + j + k];
            s += v * v;
        }
        T[r * ST + j] = s;
    }
    __syncthreads();
    float* dst = out + (long)blockIdx.z * HWSZ;
    for (int e = tid; e < TS * TS; e += 256) {
        int pr = e >> 5, pc = e & 31;
        float s = 0.f;
#pragma unroll
        for (int k = 0; k < WIN; ++k) s += T[(pr + k) * ST + pc];
        dst[(long)(tr0 + pr) * IMG + tc0 + pc] = s;
    }
}

// ---------------------------------------------------------------------------
// Full-size (32-image) separable box passes, zero LDS, register sliding.
// H kernels: grid 4096 x 256; thread -> 8 consecutive outputs of one row.
// Image z addressing: base = (z>>3)*sB + (z&7)*sC.

// Padded register-window size: loadRowWin writes whole float4 chunks, so the
// destination array must be 4*NF elements (W=2: 16 > 14 needed; W=8: 24).
template <int W> struct WinDims {
    static constexpr int A  = (W + 3) & ~3;
    static constexpr int NU = A + W + 8;              // elements actually used
    static constexpr int NF = (NU + 3) / 4;           // float4 chunks loaded
    static constexpr int NV = NF * 4;                 // padded array size
};

template <int W>
__device__ __forceinline__ void loadRowWin(const float* __restrict__ row, int c0,
                                           float* v) {
    constexpr int A = WinDims<W>::A;
    constexpr int NF = WinDims<W>::NF;
#pragma unroll
    for (int f = 0; f < NF; ++f) {
        const int cb = c0 - A + 4 * f;
        if (cb >= 0 && cb + 3 < IMG) {
            const float4 t = *(const float4*)(row + cb);
            v[4 * f + 0] = t.x; v[4 * f + 1] = t.y;
            v[4 * f + 2] = t.z; v[4 * f + 3] = t.w;
        } else {
#pragma unroll
            for (int u = 0; u < 4; ++u) {
                const int c = cb + u;
                v[4 * f + u] = (c >= 0 && c < IMG) ? row[c] : 0.f;
            }
        }
    }
}

// H box of a raw input field -> t (plain z*HWSZ layout)
template <int W>
__global__ __launch_bounds__(256) void kHbox(const float* __restrict__ in,
                                             long sB, long sC,
                                             float* __restrict__ out) {
    constexpr int A = WinDims<W>::A;
    const int g = blockIdx.x * 256 + threadIdx.x;
    const int c0 = (g & 63) << 3, r = (g >> 6) & 511, z = g >> 15;
    const float* row = in + (long)(z >> 3) * sB + (long)(z & 7) * sC + (long)r * IMG;
    float v[WinDims<W>::NV];
    loadRowWin<W>(row, c0, v);
    float o[8];
    float s = 0.f;
#pragma unroll
    for (int i = A - W + 1; i <= A + W; ++i) s += v[i];
    o[0] = s;
#pragma unroll
    for (int j = 1; j < 8; ++j) {
        s += v[A + W + j] - v[A - W + j];
        o[j] = s;
    }
    float* dst = out + (long)z * HWSZ + (long)r * IMG + c0;
    *(float4*)dst = make_float4(o[0], o[1], o[2], o[3]);
    *(float4*)(dst + 4) = make_float4(o[4], o[5], o[6], o[7]);
}

// V box of t + epilogue da = orig - box/n. grid 2048 x 256.
template <int W>
__global__ __launch_bounds__(256) void kVda(const float* __restrict__ t,
                                            const float* __restrict__ orig,
                                            long sB, long sC,
                                            float* __restrict__ out) {
    constexpr int NR = 2 * W + 15, NN = 4 * W * W;
    const int g = blockIdx.x * 256 + threadIdx.x;
    const int c = g & 511, rc = (g >> 9) & 31, z = g >> 14;
    const int r0 = rc * 16;
    const float* tz = t + (long)z * HWSZ + c;
    float v[NR];
#pragma unroll
    for (int i = 0; i < NR; ++i) {
        const int rr = r0 - W + 1 + i;
        v[i] = (rr >= 0 && rr < IMG) ? tz[(long)rr * IMG] : 0.f;
    }
    const float* oz = orig + (long)(z >> 3) * sB + (long)(z & 7) * sC + c;
    float* dst = out + (long)z * HWSZ + c;
    float s = 0.f;
#pragma unroll
    for (int i = 0; i < 2 * W; ++i) s += v[i];
#pragma unroll
    for (int j = 0; j < 16; ++j) {
        dst[(long)(r0 + j) * IMG] = oz[(long)(r0 + j) * IMG] - s * (1.0f / NN);
        if (j < 15) s += v[2 * W + j] - v[j];
    }
}

// H box of (da*dshared) and (da*da). da: z*HWSZ; dshared: (z>>3)*HWSZ.
template <int W>
__global__ __launch_bounds__(256) void kHprod(const float* __restrict__ da,
                                              const float* __restrict__ dsh,
                                              float* __restrict__ o1,
                                              float* __restrict__ o2) {
    constexpr int A = WinDims<W>::A;
    constexpr int NU = WinDims<W>::NU;
    constexpr int NV = WinDims<W>::NV;
    const int g = blockIdx.x * 256 + threadIdx.x;
    const int c0 = (g & 63) << 3, r = (g >> 6) & 511, z = g >> 15;
    const float* rowa = da + (long)z * HWSZ + (long)r * IMG;
    const float* rows = dsh + (long)(z >> 3) * HWSZ + (long)r * IMG;
    float va[NV], vs[NV];
    loadRowWin<W>(rowa, c0, va);
    loadRowWin<W>(rows, c0, vs);
    float p1[NV], p2[NV];
#pragma unroll
    for (int i = 0; i < NU; ++i) { p1[i] = va[i] * vs[i]; p2[i] = va[i] * va[i]; }
    float a[8], b[8];
    float s1 = 0.f, s2 = 0.f;
#pragma unroll
    for (int i = A - W + 1; i <= A + W; ++i) { s1 += p1[i]; s2 += p2[i]; }
    a[0] = s1; b[0] = s2;
#pragma unroll
    for (int j = 1; j < 8; ++j) {
        s1 += p1[A + W + j] - p1[A - W + j];
        s2 += p2[A + W + j] - p2[A - W + j];
        a[j] = s1; b[j] = s2;
    }
    float* d1 = o1 + (long)z * HWSZ + (long)r * IMG + c0;
    float* d2 = o2 + (long)z * HWSZ + (long)r * IMG + c0;
    *(float4*)d1 = make_float4(a[0], a[1], a[2], a[3]);
    *(float4*)(d1 + 4) = make_float4(a[4], a[5], a[6], a[7]);
    *(float4*)d2 = make_float4(b[0], b[1], b[2], b[3]);
    *(float4*)(d2 + 4) = make_float4(b[4], b[5], b[6], b[7]);
}

// V box of pH1/pH2 (w=8) + epilogue thr = 1 - sab/(sqrt(saa*sbb)+eps)
__global__ __launch_bounds__(256) void kVfin8(const float* __restrict__ pH1,
                                              const float* __restrict__ pH2,
                                              const float* __restrict__ saa,
                                              float* __restrict__ thr) {
    constexpr int W = 8, NR = 2 * W + 15;
    const int g = blockIdx.x * 256 + threadIdx.x;
    const int c = g & 511, rc = (g >> 9) & 31, z = g >> 14;
    const int r0 = rc * 16, b = z >> 3;
    const float* t1 = pH1 + (long)z * HWSZ + c;
    const float* t2 = pH2 + (long)z * HWSZ + c;
    float v1[NR], v2[NR];
#pragma unroll
    for (int i = 0; i < NR; ++i) {
        const int rr = r0 - W + 1 + i;
        const bool ok = (rr >= 0 && rr < IMG);
        v1[i] = ok ? t1[(long)rr * IMG] : 0.f;
        v2[i] = ok ? t2[(long)rr * IMG] : 0.f;
    }
    const float* sz = saa + (long)b * HWSZ + c;
    float* dst = thr + (long)z * HWSZ + c;
    float s1 = 0.f, s2 = 0.f;
#pragma unroll
    for (int i = 0; i < 2 * W; ++i) { s1 += v1[i]; s2 += v2[i]; }
#pragma unroll
    for (int j = 0; j < 16; ++j) {
        const float sa = sz[(long)(r0 + j) * IMG];
        const float den = sqrtf(fmaxf(sa * s2, 0.f)) + 1e-20f;
        dst[(long)(r0 + j) * IMG] = 1.0f - s1 / den;
        if (j < 15) {
            s1 += v1[2 * W + j] - v1[j];
            s2 += v2[2 * W + j] - v2[j];
        }
    }
}

// V box of qH1/qH2 (w=2) + epilogue: Xc, X, compare vs thr, reduce Y.
__global__ __launch_bounds__(256) void kVfin2(const float* __restrict__ qH1,
                                              const float* __restrict__ qH2,
                                              const float* __restrict__ sbb,
                                              const float* __restrict__ thr,
                                              double* __restrict__ acc) {
    constexpr int W = 2, NR = 2 * W + 15;
    __shared__ double red[4];
    const int g = blockIdx.x * 256 + threadIdx.x;
    const int c = g & 511, rc = (g >> 9) & 31, z = g >> 14;
    const int r0 = rc * 16, b = z >> 3;
    const float* t1 = qH1 + (long)z * HWSZ + c;
    const float* t2 = qH2 + (long)z * HWSZ + c;
    float v1[NR], v2[NR];
#pragma unroll
    for (int i = 0; i < NR; ++i) {
        const int rr = r0 - W + 1 + i;
        const bool ok = (rr >= 0 && rr < IMG);
        v1[i] = ok ? t1[(long)rr * IMG] : 0.f;
        v2[i] = ok ? t2[(long)rr * IMG] : 0.f;
    }
    const float* sz = sbb + (long)b * HWSZ + c;
    const float* tz = thr + (long)z * HWSZ + c;
    float s1 = 0.f, s2 = 0.f;
#pragma unroll
    for (int i = 0; i < 2 * W; ++i) { s1 += v1[i]; s2 += v2[i]; }
    double ysum = 0.0;
#pragma unroll
    for (int j = 0; j < 16; ++j) {
        const float sb = sz[(long)(r0 + j) * IMG];
        const float den = sqrtf(fmaxf(s2 * sb, 0.f)) + 1e-20f;
        const float Xc = s1 / den;
        const float X = 1.0f - fmaxf(Xc, -1.0f);
        const float th = tz[(long)(r0 + j) * IMG];
        if (X > th) ysum += (double)X;
        if (j < 15) {
            s1 += v1[2 * W + j] - v1[j];
            s2 += v2[2 * W + j] - v2[j];
        }
    }
    blockReduceAtomicAdd(ysum, acc + 2, red);
}

// ---------------------------------------------------------------------------
// L_spec: strided MTF conv of outputs (rank-1 factored), H then V+reduce.
__global__ __launch_bounds__(128) void k_spec_h(const float* __restrict__ outputs,
                                                const float* __restrict__ mtf,
                                                float* __restrict__ tmpS) {
    __shared__ float vrow[41];
    const int z = blockIdx.y, r = blockIdx.x, cs = threadIdx.x;
    const int band = z & 7;
    if (threadIdx.x < 41)
        vrow[threadIdx.x] = mtf[band * 1681 + 20 * 41 + threadIdx.x] /
                            sqrtf(mtf[band * 1681 + 20 * 41 + 20]);
    __syncthreads();
    const float* src = outputs + (long)z * HWSZ + (long)r * IMG;
    float s = 0.f;
    const int cbase = 2 + 4 * cs - 20;
#pragma unroll
    for (int j = 0; j < 41; ++j) {
        int c = cbase + j;
        if (c >= 0 && c < IMG) s += vrow[j] * src[c];
    }
    tmpS[((long)z * IMG + r) * 128 + cs] = s;
}

__global__ __launch_bounds__(256) void k_spec_v(const float* __restrict__ tmpS,
                                                const float* __restrict__ labels,
                                                const float* __restrict__ spec,
                                                const float* __restrict__ mtf,
                                                double* __restrict__ acc) {
    __shared__ double redT[4];
    __shared__ double redM[4];
    const int idx = blockIdx.x * 256 + threadIdx.x;
    const int cs = idx & 127, rs = (idx >> 7) & 127, z = idx >> 14;
    const int b = z >> 3, band = z & 7;
    __shared__ float ucol[41];
    if (threadIdx.x < 41)
        ucol[threadIdx.x] = mtf[band * 1681 + threadIdx.x * 41 + 20] /
                            sqrtf(mtf[band * 1681 + 20 * 41 + 20]);
    __syncthreads();
    const float* col = tmpS + (long)z * IMG * 128 + cs;
    float x = 0.f;
    const int rbase = 2 + 4 * rs - 20;
#pragma unroll
    for (int i = 0; i < 41; ++i) {
        int r = rbase + i;
        if (r >= 0 && r < IMG) x += ucol[i] * col[(long)r * 128];
    }
    const int gr = 2 + 4 * rs, gc = 2 + 4 * cs;
    float m = spec[(long)band * HWSZ + (long)gr * IMG + gc];
    float y = labels[((long)b * 9 + band) * HWSZ + (long)gr * IMG + gc];
    float t = fabsf(x * m - y * m);
    blockReduceAtomicAdd((double)t, acc + 0, redT);
    blockReduceAtomicAdd((double)m, acc + 1, redM);
}

__global__ void k_final(const double* __restrict__ acc, float* __restrict__ out) {
    double lspec = acc[0] / acc[1];
    double lstruct = acc[2] / (double)(NBATCH * NBANDS * HWSZ);
    out[0] = (float)(lspec + 0.25 * lstruct);
}

// ---------------------------------------------------------------------------
extern "C" void kernel_launch(void* const* d_in, const int* in_sizes, int n_in,
                              void* d_out, int out_size, void* d_ws, size_t ws_size,
                              hipStream_t stream) {
    const float* outputs = (const float*)d_in[0];   // (4,8,512,512)
    const float* labels  = (const float*)d_in[1];   // (4,9,512,512)
    const float* inp     = (const float*)d_in[2];   // (4,9,512,512)
    const float* mtf     = (const float*)d_in[3];   // (8,1,41,41)
    const float* spec    = (const float*)d_in[4];   // (1,8,512,512)
    float* out = (float*)d_out;

    const long IMGB = (long)HWSZ;     // one image in floats
    char* ws = (char*)d_ws;
    double* acc    = (double*)ws;                    // 4 doubles
    float* panf    = (float*)(ws + 1024);            // 4 imgs
    float* tmpH    = panf   + NBATCH * IMGB;         // 4 imgs
    float* da_pan8 = tmpH   + NBATCH * IMGB;         // 4 imgs
    float* saa8    = da_pan8 + NBATCH * IMGB;        // 4 imgs
    float* db_pan2 = saa8   + NBATCH * IMGB;         // 4 imgs
    float* sbb2    = db_pan2 + NBATCH * IMGB;        // 4 imgs
    float* tmpS    = sbb2   + NBATCH * IMGB;         // 8 imgs (4*8*512*128)
    float* bufA    = tmpS   + 8 * IMGB;              // 32 imgs
    float* bufB    = bufA   + 32 * IMGB;             // 32 imgs
    float* bufC    = bufB   + 32 * IMGB;             // 32 imgs
    float* bufD    = bufC   + 32 * IMGB;             // 32 imgs

    hipMemsetAsync(acc, 0, 4 * sizeof(double), stream);

    // --- per-batch shared fields -----------------------------------------
    k_pan_h<<<dim3(2, 512, NBATCH), 256, 0, stream>>>(inp, mtf, tmpH);
    k_pan_v<<<dim3(2, 512, NBATCH), 256, 0, stream>>>(tmpH, mtf, panf);
    k_da<8><<<dim3(16, 16, NBATCH), 256, 0, stream>>>(panf, (long)HWSZ, da_pan8);
    k_sq<8><<<dim3(16, 16, NBATCH), 256, 0, stream>>>(da_pan8, saa8);
    k_da<2><<<dim3(16, 16, NBATCH), 256, 0, stream>>>(labels + 8 * IMGB,
                                                      (long)9 * HWSZ, db_pan2);
    k_sq<2><<<dim3(16, 16, NBATCH), 256, 0, stream>>>(db_pan2, sbb2);

    // --- L_spec ----------------------------------------------------------
    k_spec_h<<<dim3(512, 32), 128, 0, stream>>>(outputs, mtf, tmpS);
    k_spec_v<<<dim3(2048), 256, 0, stream>>>(tmpS, labels, spec, mtf, acc);

    // --- w=8 pipeline: thr ------------------------------------------------
    kHbox<8><<<4096, 256, 0, stream>>>(inp, 9 * IMGB, IMGB, bufA);
    kVda<8><<<2048, 256, 0, stream>>>(bufA, inp, 9 * IMGB, IMGB, bufB);   // da_ms
    kHprod<8><<<4096, 256, 0, stream>>>(bufB, da_pan8, bufC, bufD);
    kVfin8<<<2048, 256, 0, stream>>>(bufC, bufD, saa8, bufA);             // thr

    // --- w=2 pipeline: X, Y reduce ---------------------------------------
    kHbox<2><<<4096, 256, 0, stream>>>(outputs, 8 * IMGB, IMGB, bufB);
    kVda<2><<<2048, 256, 0, stream>>>(bufB, outputs, 8 * IMGB, IMGB, bufC); // da_out
    kHprod<2><<<4096, 256, 0, stream>>>(bufC, db_pan2, bufB, bufD);
    kVfin2<<<2048, 256, 0, stream>>>(bufB, bufD, sbb2, bufA, acc);

    k_final<<<1, 1, 0, stream>>>(acc, out);
}

// Round 4
// 424.225 us; speedup vs baseline: 2.1006x; 1.1357x over previous
//
#include <hip/hip_runtime.h>
#include <hip/hip_bf16.h>

// Problem constants
#define HWSZ   262144   // 512*512
#define IMG    512
#define NBATCH 4
#define NBANDS 8

// ---------------------------------------------------------------------------
// Block-level reduction: wave shuffle + LDS + one double atomic per block.
__device__ __forceinline__ void blockReduceAtomicAdd(double v, double* target,
                                                     double* red) {
    for (int off = 32; off > 0; off >>= 1) v += __shfl_down(v, off, 64);
    const int wave = threadIdx.x >> 6, lane = threadIdx.x & 63;
    if (lane == 0) red[wave] = v;
    __syncthreads();
    if (threadIdx.x == 0) atomicAdd(target, red[0] + red[1] + red[2] + red[3]);
}

// ---------------------------------------------------------------------------
// Pan smoothing (edge-pad 41x41 Gaussian, rank-1 factored), horizontal pass.
__global__ __launch_bounds__(256) void k_pan_h(const float* __restrict__ inp,
                                               const float* __restrict__ mtf,
                                               float* __restrict__ tmpH) {
    __shared__ float seg[296];
    __shared__ float vrow[41];
    const int tid = threadIdx.x;
    const int b = blockIdx.z, r = blockIdx.y, c0 = blockIdx.x * 256;
    if (tid < 41) vrow[tid] = mtf[20 * 41 + tid] / sqrtf(mtf[20 * 41 + 20]);
    const float* pan = inp + ((long)b * 9 + 8) * HWSZ + (long)r * IMG;
    for (int e = tid; e < 296; e += 256) {
        int c = c0 - 20 + e;
        c = min(max(c, 0), IMG - 1);
        seg[e] = pan[c];
    }
    __syncthreads();
    float s = 0.f;
#pragma unroll
    for (int j = 0; j < 41; ++j) s += vrow[j] * seg[tid + j];
    tmpH[(long)b * HWSZ + (long)r * IMG + c0 + tid] = s;
}

__global__ __launch_bounds__(256) void k_pan_v(const float* __restrict__ tmpH,
                                               const float* __restrict__ mtf,
                                               float* __restrict__ panf) {
    __shared__ float ucol[41];
    const int tid = threadIdx.x;
    const int b = blockIdx.z, r = blockIdx.y, c = blockIdx.x * 256 + tid;
    if (tid < 41) ucol[tid] = mtf[tid * 41 + 20] / sqrtf(mtf[20 * 41 + 20]);
    __syncthreads();
    const float* base = tmpH + (long)b * HWSZ;
    float s = 0.f;
#pragma unroll
    for (int i = 0; i < 41; ++i) {
        int rr = min(max(r - 20 + i, 0), IMG - 1);
        s += ucol[i] * base[(long)rr * IMG + c];
    }
    panf[(long)b * HWSZ + (long)r * IMG + c] = s;
}

// ---------------------------------------------------------------------------
// Small-field (4-image) helpers, LDS tile based (cheap at this size).
template <int W>
__global__ __launch_bounds__(256) void k_da(const float* __restrict__ in,
                                            long inBatchStride,
                                            float* __restrict__ out) {
    constexpr int TS = 32, WIN = 2 * W, NN = 4 * W * W, RE = TS + WIN - 1;
    constexpr int SR = RE;
    constexpr int ST = 33;
    __shared__ float RAW[RE * SR];
    __shared__ float T[RE * ST];
    const int tid = threadIdx.x;
    const int tr0 = blockIdx.y * TS, tc0 = blockIdx.x * TS;
    const float* src = in + (long)blockIdx.z * inBatchStride;
    for (int e = tid; e < RE * RE; e += 256) {
        int r = e / RE, c = e % RE;
        int gr = tr0 - (W - 1) + r, gc = tc0 - (W - 1) + c;
        float v = 0.f;
        if (gr >= 0 && gr < IMG && gc >= 0 && gc < IMG) v = src[(long)gr * IMG + gc];
        RAW[r * SR + c] = v;
    }
    __syncthreads();
    for (int e = tid; e < RE * TS; e += 256) {
        int r = e >> 5, j = e & 31;
        float s = 0.f;
#pragma unroll
        for (int k = 0; k < WIN; ++k) s += RAW[r * SR + j + k];
        T[r * ST + j] = s;
    }
    __syncthreads();
    float* dst = out + (long)blockIdx.z * HWSZ;
    for (int e = tid; e < TS * TS; e += 256) {
        int pr = e >> 5, pc = e & 31;
        float s = 0.f;
#pragma unroll
        for (int k = 0; k < WIN; ++k) s += T[(pr + k) * ST + pc];
        float da = RAW[(pr + W - 1) * SR + (pc + W - 1)] - s * (1.0f / NN);
        dst[(long)(tr0 + pr) * IMG + tc0 + pc] = da;
    }
}

template <int W>
__global__ __launch_bounds__(256) void k_sq(const float* __restrict__ in,
                                            float* __restrict__ out) {
    constexpr int TS = 32, WIN = 2 * W, RE = TS + WIN - 1;
    constexpr int SR = RE, ST = 33;
    __shared__ float RAW[RE * SR];
    __shared__ float T[RE * ST];
    const int tid = threadIdx.x;
    const int tr0 = blockIdx.y * TS, tc0 = blockIdx.x * TS;
    const float* src = in + (long)blockIdx.z * HWSZ;
    for (int e = tid; e < RE * RE; e += 256) {
        int r = e / RE, c = e % RE;
        int gr = tr0 - (W - 1) + r, gc = tc0 - (W - 1) + c;
        float v = 0.f;
        if (gr >= 0 && gr < IMG && gc >= 0 && gc < IMG) v = src[(long)gr * IMG + gc];
        RAW[r * SR + c] = v;
    }
    __syncthreads();
    for (int e = tid; e < RE * TS; e += 256) {
        int r = e >> 5, j = e & 31;
        float s = 0.f;
#pragma unroll
        for (int k = 0; k < WIN; ++k) {
            float v = RAW[r * SR + j + k];
            s += v * v;
        }
        T[r * ST + j] = s;
    }
    __syncthreads();
    float* dst = out + (long)blockIdx.z * HWSZ;
    for (int e = tid; e < TS * TS; e += 256) {
        int pr = e >> 5, pc = e & 31;
        float s = 0.f;
#pragma unroll
        for (int k = 0; k < WIN; ++k) s += T[(pr + k) * ST + pc];
        dst[(long)(tr0 + pr) * IMG + tc0 + pc] = s;
    }
}

// ---------------------------------------------------------------------------
// Fused stage A: da = raw - box2d(raw)/n, tiled H+V in LDS.
// Tile TSRxTSC(=64) outputs; halo W-1 left/up, W right/down (zero pad).
// Grid (512/64, 512/TSR, 32), block 256.
template <int W, int TSR>
__global__ __launch_bounds__(256) void kFusedA(const float* __restrict__ in,
                                               long sB, long sC,
                                               float* __restrict__ out) {
    constexpr int TSC = 64;
    constexpr int ERE = TSR + 2 * W - 1;   // row extent (incl halo)
    constexpr int ECE = TSC + 2 * W - 1;   // col extent (odd: 79 or 67)
    constexpr int SR = ECE;                // RAW stride (odd)
    constexpr int ST = 65;                 // T stride (odd)
    constexpr int NN = 4 * W * W;
    constexpr int SEGSH = (W == 8) ? 2 : 3;           // log2(#segments)
    constexpr int SEGW = TSC >> SEGSH;                // 16 or 8
    __shared__ float RAW[ERE * SR];
    __shared__ float T[ERE * ST];
    const int tid = threadIdx.x;
    const int R0 = blockIdx.y * TSR, C0 = blockIdx.x * TSC;
    const int z = blockIdx.z;
    const float* src = in + (long)(z >> 3) * sB + (long)(z & 7) * sC;

    for (int e = tid; e < ERE * ECE; e += 256) {
        const int r = e / ECE, c = e - r * ECE;
        const int gr = R0 - (W - 1) + r, gc = C0 - (W - 1) + c;
        RAW[e] = (gr >= 0 && gr < IMG && gc >= 0 && gc < IMG)
                     ? src[(long)gr * IMG + gc] : 0.f;
    }
    __syncthreads();

    // H box: T[r][c] = sum_{k<2W} RAW[r][c+k]
    for (int e = tid; e < (ERE << SEGSH); e += 256) {
        const int r = e >> SEGSH, c0 = (e & ((1 << SEGSH) - 1)) * SEGW;
        const float* Rr = RAW + r * SR;
        float s = 0.f;
#pragma unroll
        for (int k = 0; k < 2 * W; ++k) s += Rr[c0 + k];
        float* Tr = T + r * ST;
        Tr[c0] = s;
#pragma unroll
        for (int j = 1; j < SEGW; ++j) {
            s += Rr[c0 + j + 2 * W - 1] - Rr[c0 + j - 1];
            Tr[c0 + j] = s;
        }
    }
    __syncthreads();

    // V box + epilogue
    constexpr int RPT = TSR / 4;
    const int c = tid & 63, r0 = (tid >> 6) * RPT;
    float s = 0.f;
#pragma unroll
    for (int k = 0; k < 2 * W; ++k) s += T[(r0 + k) * ST + c];
    float* dst = out + (long)z * HWSZ + (long)R0 * IMG + C0 + c;
#pragma unroll
    for (int j = 0; j < RPT; ++j) {
        const int r = r0 + j;
        const float center = RAW[(r + W - 1) * SR + (c + W - 1)];
        dst[(long)r * IMG] = center - s * (1.0f / NN);
        if (j < RPT - 1) s += T[(r + 2 * W) * ST + c] - T[r * ST + c];
    }
}

// ---------------------------------------------------------------------------
// Fused stage B: per-tile product boxes + xcorr epilogue.
// P1 = da*dsh, P2 = da*da in LDS (with halo), H-box both into T1/T2,
// V-box + epilogue. FINAL=false: write thr. FINAL=true: reduce Y into acc.
// Grid (8, 512/TSR, 32), block 256.
template <int W, int TSR, bool FINAL>
__global__ __launch_bounds__(256) void kFusedB(const float* __restrict__ da,
                                               const float* __restrict__ dsh,
                                               const float* __restrict__ sxx,
                                               const float* __restrict__ thrIn,
                                               float* __restrict__ thrOut,
                                               double* __restrict__ acc) {
    constexpr int TSC = 64;
    constexpr int ERE = TSR + 2 * W - 1;
    constexpr int ECE = TSC + 2 * W - 1;   // odd
    constexpr int SR = ECE;
    constexpr int ST = 65;
    constexpr int SEGSH = (W == 8) ? 2 : 3;
    constexpr int SEGW = TSC >> SEGSH;
    __shared__ float P1[ERE * SR];
    __shared__ float P2[ERE * SR];
    __shared__ float T1[ERE * ST];
    __shared__ float T2[ERE * ST];
    __shared__ double red[4];
    const int tid = threadIdx.x;
    const int R0 = blockIdx.y * TSR, C0 = blockIdx.x * TSC;
    const int z = blockIdx.z, b = z >> 3;
    const float* za = da + (long)z * HWSZ;
    const float* zs = dsh + (long)b * HWSZ;

    for (int e = tid; e < ERE * ECE; e += 256) {
        const int r = e / ECE, c = e - r * ECE;
        const int gr = R0 - (W - 1) + r, gc = C0 - (W - 1) + c;
        float a = 0.f, sv = 0.f;
        if (gr >= 0 && gr < IMG && gc >= 0 && gc < IMG) {
            const long o = (long)gr * IMG + gc;
            a = za[o];
            sv = zs[o];
        }
        P1[e] = a * sv;
        P2[e] = a * a;
    }
    __syncthreads();

    for (int e = tid; e < (ERE << SEGSH); e += 256) {
        const int r = e >> SEGSH, c0 = (e & ((1 << SEGSH) - 1)) * SEGW;
        const float* R1 = P1 + r * SR;
        const float* R2 = P2 + r * SR;
        float s1 = 0.f, s2 = 0.f;
#pragma unroll
        for (int k = 0; k < 2 * W; ++k) { s1 += R1[c0 + k]; s2 += R2[c0 + k]; }
        float* t1 = T1 + r * ST;
        float* t2 = T2 + r * ST;
        t1[c0] = s1; t2[c0] = s2;
#pragma unroll
        for (int j = 1; j < SEGW; ++j) {
            s1 += R1[c0 + j + 2 * W - 1] - R1[c0 + j - 1];
            s2 += R2[c0 + j + 2 * W - 1] - R2[c0 + j - 1];
            t1[c0 + j] = s1; t2[c0 + j] = s2;
        }
    }
    __syncthreads();

    constexpr int RPT = TSR / 4;
    const int c = tid & 63, r0 = (tid >> 6) * RPT;
    float s1 = 0.f, s2 = 0.f;
#pragma unroll
    for (int k = 0; k < 2 * W; ++k) {
        s1 += T1[(r0 + k) * ST + c];
        s2 += T2[(r0 + k) * ST + c];
    }
    const long obase = (long)z * HWSZ + (long)R0 * IMG + C0 + c;
    const long sbase = (long)b * HWSZ + (long)R0 * IMG + C0 + c;
    double ysum = 0.0;
#pragma unroll
    for (int j = 0; j < RPT; ++j) {
        const int r = r0 + j;
        const float sxv = sxx[sbase + (long)r * IMG];
        if (!FINAL) {
            // thr = 1 - s_ab/(sqrt(s_aa*s_bb)+eps); s_aa = shared (pan_f)
            const float den = sqrtf(fmaxf(sxv * s2, 0.f)) + 1e-20f;
            thrOut[obase + (long)r * IMG] = 1.0f - s1 / den;
        } else {
            // Xc = s_ab/(sqrt(s_aa*s_bb)+eps); s_aa = in-tile (outputs)
            const float den = sqrtf(fmaxf(s2 * sxv, 0.f)) + 1e-20f;
            const float Xc = s1 / den;
            const float X = 1.0f - fmaxf(Xc, -1.0f);
            const float th = thrIn[obase + (long)r * IMG];
            if (X > th) ysum += (double)X;
        }
        if (j < RPT - 1) {
            s1 += T1[(r + 2 * W) * ST + c] - T1[r * ST + c];
            s2 += T2[(r + 2 * W) * ST + c] - T2[r * ST + c];
        }
    }
    if (FINAL) blockReduceAtomicAdd(ysum, acc + 2, red);
}

// ---------------------------------------------------------------------------
// L_spec: strided MTF conv of outputs (rank-1 factored), H then V+reduce.
// New H pass: 4 strided outputs/thread from 14 float4 register loads.
// grid 2048 x 256. Thread: q=col-group (0..31), r=row, z=image.
__global__ __launch_bounds__(256) void k_spec_h(const float* __restrict__ outputs,
                                                const float* __restrict__ mtf,
                                                float* __restrict__ tmpS) {
    __shared__ float vrow[41];
    const int g = blockIdx.x * 256 + threadIdx.x;
    const int q = g & 31, r = (g >> 5) & 511, z = g >> 14;   // z uniform/block
    const int band = z & 7;
    if (threadIdx.x < 41)
        vrow[threadIdx.x] = mtf[band * 1681 + 20 * 41 + threadIdx.x] /
                            sqrtf(mtf[band * 1681 + 20 * 41 + 20]);
    __syncthreads();
    const float* row = outputs + (long)z * HWSZ + (long)r * IMG;
    // input cols 16q-20 .. 16q+35 (zero pad outside)
    float v[56];
#pragma unroll
    for (int f = 0; f < 14; ++f) {
        const int cb = 16 * q - 20 + 4 * f;
        if (cb >= 0 && cb + 3 < IMG) {
            const float4 t = *(const float4*)(row + cb);
            v[4 * f + 0] = t.x; v[4 * f + 1] = t.y;
            v[4 * f + 2] = t.z; v[4 * f + 3] = t.w;
        } else {
#pragma unroll
            for (int u = 0; u < 4; ++u) {
                const int cc = cb + u;
                v[4 * f + u] = (cc >= 0 && cc < IMG) ? row[cc] : 0.f;
            }
        }
    }
    float o[4] = {0.f, 0.f, 0.f, 0.f};
#pragma unroll
    for (int j = 0; j < 41; ++j) {
        const float w = vrow[j];
#pragma unroll
        for (int u = 0; u < 4; ++u) o[u] += w * v[2 + 4 * u + j];
    }
    float* dst = tmpS + ((long)z * IMG + r) * 128 + 4 * q;
    *(float4*)dst = make_float4(o[0], o[1], o[2], o[3]);
}

__global__ __launch_bounds__(256) void k_spec_v(const float* __restrict__ tmpS,
                                                const float* __restrict__ labels,
                                                const float* __restrict__ spec,
                                                const float* __restrict__ mtf,
                                                double* __restrict__ acc) {
    __shared__ double redT[4];
    __shared__ double redM[4];
    const int idx = blockIdx.x * 256 + threadIdx.x;
    const int cs = idx & 127, rs = (idx >> 7) & 127, z = idx >> 14;
    const int b = z >> 3, band = z & 7;
    __shared__ float ucol[41];
    if (threadIdx.x < 41)
        ucol[threadIdx.x] = mtf[band * 1681 + threadIdx.x * 41 + 20] /
                            sqrtf(mtf[band * 1681 + 20 * 41 + 20]);
    __syncthreads();
    const float* col = tmpS + (long)z * IMG * 128 + cs;
    float x = 0.f;
    const int rbase = 2 + 4 * rs - 20;
#pragma unroll
    for (int i = 0; i < 41; ++i) {
        int r = rbase + i;
        if (r >= 0 && r < IMG) x += ucol[i] * col[(long)r * 128];
    }
    const int gr = 2 + 4 * rs, gc = 2 + 4 * cs;
    float m = spec[(long)band * HWSZ + (long)gr * IMG + gc];
    float y = labels[((long)b * 9 + band) * HWSZ + (long)gr * IMG + gc];
    float t = fabsf(x * m - y * m);
    blockReduceAtomicAdd((double)t, acc + 0, redT);
    blockReduceAtomicAdd((double)m, acc + 1, redM);
}

__global__ void k_final(const double* __restrict__ acc, float* __restrict__ out) {
    double lspec = acc[0] / acc[1];
    double lstruct = acc[2] / (double)(NBATCH * NBANDS * HWSZ);
    out[0] = (float)(lspec + 0.25 * lstruct);
}

// ---------------------------------------------------------------------------
extern "C" void kernel_launch(void* const* d_in, const int* in_sizes, int n_in,
                              void* d_out, int out_size, void* d_ws, size_t ws_size,
                              hipStream_t stream) {
    const float* outputs = (const float*)d_in[0];   // (4,8,512,512)
    const float* labels  = (const float*)d_in[1];   // (4,9,512,512)
    const float* inp     = (const float*)d_in[2];   // (4,9,512,512)
    const float* mtf     = (const float*)d_in[3];   // (8,1,41,41)
    const float* spec    = (const float*)d_in[4];   // (1,8,512,512)
    float* out = (float*)d_out;

    const long IMGB = (long)HWSZ;     // one image in floats
    char* ws = (char*)d_ws;
    double* acc    = (double*)ws;                    // 4 doubles
    float* panf    = (float*)(ws + 1024);            // 4 imgs
    float* tmpH    = panf   + NBATCH * IMGB;         // 4 imgs
    float* da_pan8 = tmpH   + NBATCH * IMGB;         // 4 imgs
    float* saa8    = da_pan8 + NBATCH * IMGB;        // 4 imgs
    float* db_pan2 = saa8   + NBATCH * IMGB;         // 4 imgs
    float* sbb2    = db_pan2 + NBATCH * IMGB;        // 4 imgs
    float* tmpS    = sbb2   + NBATCH * IMGB;         // 8 imgs
    float* bufDA   = tmpS   + 8 * IMGB;              // 32 imgs (reused)
    float* bufTHR  = bufDA  + 32 * IMGB;             // 32 imgs

    hipMemsetAsync(acc, 0, 4 * sizeof(double), stream);

    // --- per-batch shared fields -----------------------------------------
    k_pan_h<<<dim3(2, 512, NBATCH), 256, 0, stream>>>(inp, mtf, tmpH);
    k_pan_v<<<dim3(2, 512, NBATCH), 256, 0, stream>>>(tmpH, mtf, panf);
    k_da<8><<<dim3(16, 16, NBATCH), 256, 0, stream>>>(panf, (long)HWSZ, da_pan8);
    k_sq<8><<<dim3(16, 16, NBATCH), 256, 0, stream>>>(da_pan8, saa8);
    k_da<2><<<dim3(16, 16, NBATCH), 256, 0, stream>>>(labels + 8 * IMGB,
                                                      (long)9 * HWSZ, db_pan2);
    k_sq<2><<<dim3(16, 16, NBATCH), 256, 0, stream>>>(db_pan2, sbb2);

    // --- L_spec ----------------------------------------------------------
    k_spec_h<<<2048, 256, 0, stream>>>(outputs, mtf, tmpS);
    k_spec_v<<<dim3(2048), 256, 0, stream>>>(tmpS, labels, spec, mtf, acc);

    // --- w=8 pipeline: thr (fused H+V per stage) -------------------------
    kFusedA<8, 64><<<dim3(8, 8, 32), 256, 0, stream>>>(inp, 9 * IMGB, IMGB, bufDA);
    kFusedB<8, 32, false><<<dim3(8, 16, 32), 256, 0, stream>>>(
        bufDA, da_pan8, saa8, nullptr, bufTHR, nullptr);

    // --- w=2 pipeline: X, Y reduce ---------------------------------------
    kFusedA<2, 64><<<dim3(8, 8, 32), 256, 0, stream>>>(outputs, 8 * IMGB, IMGB, bufDA);
    kFusedB<2, 32, true><<<dim3(8, 16, 32), 256, 0, stream>>>(
        bufDA, db_pan2, sbb2, bufTHR, nullptr, acc);

    k_final<<<1, 1, 0, stream>>>(acc, out);
}

// Round 5
// 414.696 us; speedup vs baseline: 2.1489x; 1.0230x over previous
//
#include <hip/hip_runtime.h>
#include <hip/hip_bf16.h>

// Problem constants
#define HWSZ   262144   // 512*512
#define IMG    512
#define NBATCH 4
#define NBANDS 8

// ---------------------------------------------------------------------------
// Block-level reduction: wave shuffle + LDS + one double atomic per block.
__device__ __forceinline__ void blockReduceAtomicAdd(double v, double* target,
                                                     double* red) {
    for (int off = 32; off > 0; off >>= 1) v += __shfl_down(v, off, 64);
    const int wave = threadIdx.x >> 6, lane = threadIdx.x & 63;
    if (lane == 0) red[wave] = v;
    __syncthreads();
    if (threadIdx.x == 0) atomicAdd(target, red[0] + red[1] + red[2] + red[3]);
}

// ---------------------------------------------------------------------------
// Pan smoothing (edge-pad 41x41 Gaussian, rank-1 factored), horizontal pass.
__global__ __launch_bounds__(256) void k_pan_h(const float* __restrict__ inp,
                                               const float* __restrict__ mtf,
                                               float* __restrict__ tmpH) {
    __shared__ float seg[296];
    __shared__ float vrow[41];
    const int tid = threadIdx.x;
    const int b = blockIdx.z, r = blockIdx.y, c0 = blockIdx.x * 256;
    if (tid < 41) vrow[tid] = mtf[20 * 41 + tid] / sqrtf(mtf[20 * 41 + 20]);
    const float* pan = inp + ((long)b * 9 + 8) * HWSZ + (long)r * IMG;
    for (int e = tid; e < 296; e += 256) {
        int c = c0 - 20 + e;
        c = min(max(c, 0), IMG - 1);
        seg[e] = pan[c];
    }
    __syncthreads();
    float s = 0.f;
#pragma unroll
    for (int j = 0; j < 41; ++j) s += vrow[j] * seg[tid + j];
    tmpH[(long)b * HWSZ + (long)r * IMG + c0 + tid] = s;
}

__global__ __launch_bounds__(256) void k_pan_v(const float* __restrict__ tmpH,
                                               const float* __restrict__ mtf,
                                               float* __restrict__ panf) {
    __shared__ float ucol[41];
    const int tid = threadIdx.x;
    const int b = blockIdx.z, r = blockIdx.y, c = blockIdx.x * 256 + tid;
    if (tid < 41) ucol[tid] = mtf[tid * 41 + 20] / sqrtf(mtf[20 * 41 + 20]);
    __syncthreads();
    const float* base = tmpH + (long)b * HWSZ;
    float s = 0.f;
#pragma unroll
    for (int i = 0; i < 41; ++i) {
        int rr = min(max(r - 20 + i, 0), IMG - 1);
        s += ucol[i] * base[(long)rr * IMG + c];
    }
    panf[(long)b * HWSZ + (long)r * IMG + c] = s;
}

// ---------------------------------------------------------------------------
// Small-field (4-image) helpers, LDS tile based (cheap at this size).
template <int W>
__global__ __launch_bounds__(256) void k_da(const float* __restrict__ in,
                                            long inBatchStride,
                                            float* __restrict__ out) {
    constexpr int TS = 32, WIN = 2 * W, NN = 4 * W * W, RE = TS + WIN - 1;
    constexpr int SR = RE;
    constexpr int ST = 33;
    __shared__ float RAW[RE * SR];
    __shared__ float T[RE * ST];
    const int tid = threadIdx.x;
    const int tr0 = blockIdx.y * TS, tc0 = blockIdx.x * TS;
    const float* src = in + (long)blockIdx.z * inBatchStride;
    for (int e = tid; e < RE * RE; e += 256) {
        int r = e / RE, c = e % RE;
        int gr = tr0 - (W - 1) + r, gc = tc0 - (W - 1) + c;
        float v = 0.f;
        if (gr >= 0 && gr < IMG && gc >= 0 && gc < IMG) v = src[(long)gr * IMG + gc];
        RAW[r * SR + c] = v;
    }
    __syncthreads();
    for (int e = tid; e < RE * TS; e += 256) {
        int r = e >> 5, j = e & 31;
        float s = 0.f;
#pragma unroll
        for (int k = 0; k < WIN; ++k) s += RAW[r * SR + j + k];
        T[r * ST + j] = s;
    }
    __syncthreads();
    float* dst = out + (long)blockIdx.z * HWSZ;
    for (int e = tid; e < TS * TS; e += 256) {
        int pr = e >> 5, pc = e & 31;
        float s = 0.f;
#pragma unroll
        for (int k = 0; k < WIN; ++k) s += T[(pr + k) * ST + pc];
        float da = RAW[(pr + W - 1) * SR + (pc + W - 1)] - s * (1.0f / NN);
        dst[(long)(tr0 + pr) * IMG + tc0 + pc] = da;
    }
}

template <int W>
__global__ __launch_bounds__(256) void k_sq(const float* __restrict__ in,
                                            float* __restrict__ out) {
    constexpr int TS = 32, WIN = 2 * W, RE = TS + WIN - 1;
    constexpr int SR = RE, ST = 33;
    __shared__ float RAW[RE * SR];
    __shared__ float T[RE * ST];
    const int tid = threadIdx.x;
    const int tr0 = blockIdx.y * TS, tc0 = blockIdx.x * TS;
    const float* src = in + (long)blockIdx.z * HWSZ;
    for (int e = tid; e < RE * RE; e += 256) {
        int r = e / RE, c = e % RE;
        int gr = tr0 - (W - 1) + r, gc = tc0 - (W - 1) + c;
        float v = 0.f;
        if (gr >= 0 && gr < IMG && gc >= 0 && gc < IMG) v = src[(long)gr * IMG + gc];
        RAW[r * SR + c] = v;
    }
    __syncthreads();
    for (int e = tid; e < RE * TS; e += 256) {
        int r = e >> 5, j = e & 31;
        float s = 0.f;
#pragma unroll
        for (int k = 0; k < WIN; ++k) {
            float v = RAW[r * SR + j + k];
            s += v * v;
        }
        T[r * ST + j] = s;
    }
    __syncthreads();
    float* dst = out + (long)blockIdx.z * HWSZ;
    for (int e = tid; e < TS * TS; e += 256) {
        int pr = e >> 5, pc = e & 31;
        float s = 0.f;
#pragma unroll
        for (int k = 0; k < WIN; ++k) s += T[(pr + k) * ST + pc];
        dst[(long)(tr0 + pr) * IMG + tc0 + pc] = s;
    }
}

// ---------------------------------------------------------------------------
// Full-size (32-image) separable box passes, zero LDS, register sliding.
// H kernels: grid 4096 x 256; thread -> 8 consecutive outputs of one row.
// Image z addressing: base = (z>>3)*sB + (z&7)*sC.

// Padded register-window size: loadRowWin writes whole float4 chunks, so the
// destination array must be 4*NF elements (W=2: 16 > 14 needed; W=8: 24).
template <int W> struct WinDims {
    static constexpr int A  = (W + 3) & ~3;
    static constexpr int NU = A + W + 8;              // elements actually used
    static constexpr int NF = (NU + 3) / 4;           // float4 chunks loaded
    static constexpr int NV = NF * 4;                 // padded array size
};

template <int W>
__device__ __forceinline__ void loadRowWin(const float* __restrict__ row, int c0,
                                           float* v) {
    constexpr int A = WinDims<W>::A;
    constexpr int NF = WinDims<W>::NF;
#pragma unroll
    for (int f = 0; f < NF; ++f) {
        const int cb = c0 - A + 4 * f;
        if (cb >= 0 && cb + 3 < IMG) {
            const float4 t = *(const float4*)(row + cb);
            v[4 * f + 0] = t.x; v[4 * f + 1] = t.y;
            v[4 * f + 2] = t.z; v[4 * f + 3] = t.w;
        } else {
#pragma unroll
            for (int u = 0; u < 4; ++u) {
                const int c = cb + u;
                v[4 * f + u] = (c >= 0 && c < IMG) ? row[c] : 0.f;
            }
        }
    }
}

// H box of a raw input field -> t (plain z*HWSZ layout)
template <int W>
__global__ __launch_bounds__(256) void kHbox(const float* __restrict__ in,
                                             long sB, long sC,
                                             float* __restrict__ out) {
    constexpr int A = WinDims<W>::A;
    const int g = blockIdx.x * 256 + threadIdx.x;
    const int c0 = (g & 63) << 3, r = (g >> 6) & 511, z = g >> 15;
    const float* row = in + (long)(z >> 3) * sB + (long)(z & 7) * sC + (long)r * IMG;
    float v[WinDims<W>::NV];
    loadRowWin<W>(row, c0, v);
    float o[8];
    float s = 0.f;
#pragma unroll
    for (int i = A - W + 1; i <= A + W; ++i) s += v[i];
    o[0] = s;
#pragma unroll
    for (int j = 1; j < 8; ++j) {
        s += v[A + W + j] - v[A - W + j];
        o[j] = s;
    }
    float* dst = out + (long)z * HWSZ + (long)r * IMG + c0;
    *(float4*)dst = make_float4(o[0], o[1], o[2], o[3]);
    *(float4*)(dst + 4) = make_float4(o[4], o[5], o[6], o[7]);
}

// V box of t + epilogue da = orig - box/n. grid 2048 x 256.
template <int W>
__global__ __launch_bounds__(256) void kVda(const float* __restrict__ t,
                                            const float* __restrict__ orig,
                                            long sB, long sC,
                                            float* __restrict__ out) {
    constexpr int NR = 2 * W + 15, NN = 4 * W * W;
    const int g = blockIdx.x * 256 + threadIdx.x;
    const int c = g & 511, rc = (g >> 9) & 31, z = g >> 14;
    const int r0 = rc * 16;
    const float* tz = t + (long)z * HWSZ + c;
    float v[NR];
#pragma unroll
    for (int i = 0; i < NR; ++i) {
        const int rr = r0 - W + 1 + i;
        v[i] = (rr >= 0 && rr < IMG) ? tz[(long)rr * IMG] : 0.f;
    }
    const float* oz = orig + (long)(z >> 3) * sB + (long)(z & 7) * sC + c;
    float* dst = out + (long)z * HWSZ + c;
    float s = 0.f;
#pragma unroll
    for (int i = 0; i < 2 * W; ++i) s += v[i];
#pragma unroll
    for (int j = 0; j < 16; ++j) {
        dst[(long)(r0 + j) * IMG] = oz[(long)(r0 + j) * IMG] - s * (1.0f / NN);
        if (j < 15) s += v[2 * W + j] - v[j];
    }
}

// H box of (da*dshared) and (da*da). da: z*HWSZ; dshared: (z>>3)*HWSZ.
template <int W>
__global__ __launch_bounds__(256) void kHprod(const float* __restrict__ da,
                                              const float* __restrict__ dsh,
                                              float* __restrict__ o1,
                                              float* __restrict__ o2) {
    constexpr int A = WinDims<W>::A;
    constexpr int NU = WinDims<W>::NU;
    constexpr int NV = WinDims<W>::NV;
    const int g = blockIdx.x * 256 + threadIdx.x;
    const int c0 = (g & 63) << 3, r = (g >> 6) & 511, z = g >> 15;
    const float* rowa = da + (long)z * HWSZ + (long)r * IMG;
    const float* rows = dsh + (long)(z >> 3) * HWSZ + (long)r * IMG;
    float va[NV], vs[NV];
    loadRowWin<W>(rowa, c0, va);
    loadRowWin<W>(rows, c0, vs);
    float p1[NV], p2[NV];
#pragma unroll
    for (int i = 0; i < NU; ++i) { p1[i] = va[i] * vs[i]; p2[i] = va[i] * va[i]; }
    float a[8], b[8];
    float s1 = 0.f, s2 = 0.f;
#pragma unroll
    for (int i = A - W + 1; i <= A + W; ++i) { s1 += p1[i]; s2 += p2[i]; }
    a[0] = s1; b[0] = s2;
#pragma unroll
    for (int j = 1; j < 8; ++j) {
        s1 += p1[A + W + j] - p1[A - W + j];
        s2 += p2[A + W + j] - p2[A - W + j];
        a[j] = s1; b[j] = s2;
    }
    float* d1 = o1 + (long)z * HWSZ + (long)r * IMG + c0;
    float* d2 = o2 + (long)z * HWSZ + (long)r * IMG + c0;
    *(float4*)d1 = make_float4(a[0], a[1], a[2], a[3]);
    *(float4*)(d1 + 4) = make_float4(a[4], a[5], a[6], a[7]);
    *(float4*)d2 = make_float4(b[0], b[1], b[2], b[3]);
    *(float4*)(d2 + 4) = make_float4(b[4], b[5], b[6], b[7]);
}

// V box of pH1/pH2 (w=8) + epilogue thr = 1 - sab/(sqrt(saa*sbb)+eps)
__global__ __launch_bounds__(256) void kVfin8(const float* __restrict__ pH1,
                                              const float* __restrict__ pH2,
                                              const float* __restrict__ saa,
                                              float* __restrict__ thr) {
    constexpr int W = 8, NR = 2 * W + 15;
    const int g = blockIdx.x * 256 + threadIdx.x;
    const int c = g & 511, rc = (g >> 9) & 31, z = g >> 14;
    const int r0 = rc * 16, b = z >> 3;
    const float* t1 = pH1 + (long)z * HWSZ + c;
    const float* t2 = pH2 + (long)z * HWSZ + c;
    float v1[NR], v2[NR];
#pragma unroll
    for (int i = 0; i < NR; ++i) {
        const int rr = r0 - W + 1 + i;
        const bool ok = (rr >= 0 && rr < IMG);
        v1[i] = ok ? t1[(long)rr * IMG] : 0.f;
        v2[i] = ok ? t2[(long)rr * IMG] : 0.f;
    }
    const float* sz = saa + (long)b * HWSZ + c;
    float* dst = thr + (long)z * HWSZ + c;
    float s1 = 0.f, s2 = 0.f;
#pragma unroll
    for (int i = 0; i < 2 * W; ++i) { s1 += v1[i]; s2 += v2[i]; }
#pragma unroll
    for (int j = 0; j < 16; ++j) {
        const float sa = sz[(long)(r0 + j) * IMG];
        const float den = sqrtf(fmaxf(sa * s2, 0.f)) + 1e-20f;
        dst[(long)(r0 + j) * IMG] = 1.0f - s1 / den;
        if (j < 15) {
            s1 += v1[2 * W + j] - v1[j];
            s2 += v2[2 * W + j] - v2[j];
        }
    }
}

// V box of qH1/qH2 (w=2) + epilogue: Xc, X, compare vs thr, reduce Y.
__global__ __launch_bounds__(256) void kVfin2(const float* __restrict__ qH1,
                                              const float* __restrict__ qH2,
                                              const float* __restrict__ sbb,
                                              const float* __restrict__ thr,
                                              double* __restrict__ acc) {
    constexpr int W = 2, NR = 2 * W + 15;
    __shared__ double red[4];
    const int g = blockIdx.x * 256 + threadIdx.x;
    const int c = g & 511, rc = (g >> 9) & 31, z = g >> 14;
    const int r0 = rc * 16, b = z >> 3;
    const float* t1 = qH1 + (long)z * HWSZ + c;
    const float* t2 = qH2 + (long)z * HWSZ + c;
    float v1[NR], v2[NR];
#pragma unroll
    for (int i = 0; i < NR; ++i) {
        const int rr = r0 - W + 1 + i;
        const bool ok = (rr >= 0 && rr < IMG);
        v1[i] = ok ? t1[(long)rr * IMG] : 0.f;
        v2[i] = ok ? t2[(long)rr * IMG] : 0.f;
    }
    const float* sz = sbb + (long)b * HWSZ + c;
    const float* tz = thr + (long)z * HWSZ + c;
    float s1 = 0.f, s2 = 0.f;
#pragma unroll
    for (int i = 0; i < 2 * W; ++i) { s1 += v1[i]; s2 += v2[i]; }
    double ysum = 0.0;
#pragma unroll
    for (int j = 0; j < 16; ++j) {
        const float sb = sz[(long)(r0 + j) * IMG];
        const float den = sqrtf(fmaxf(s2 * sb, 0.f)) + 1e-20f;
        const float Xc = s1 / den;
        const float X = 1.0f - fmaxf(Xc, -1.0f);
        const float th = tz[(long)(r0 + j) * IMG];
        if (X > th) ysum += (double)X;
        if (j < 15) {
            s1 += v1[2 * W + j] - v1[j];
            s2 += v2[2 * W + j] - v2[j];
        }
    }
    blockReduceAtomicAdd(ysum, acc + 2, red);
}

// ---------------------------------------------------------------------------
// L_spec: strided MTF conv of outputs (rank-1 factored), H then V+reduce.
// H pass: 4 strided outputs/thread from 14 float4 register loads.
// grid 2048 x 256. Thread: q=col-group (0..31), r=row, z=image.
__global__ __launch_bounds__(256) void k_spec_h(const float* __restrict__ outputs,
                                                const float* __restrict__ mtf,
                                                float* __restrict__ tmpS) {
    __shared__ float vrow[41];
    const int g = blockIdx.x * 256 + threadIdx.x;
    const int q = g & 31, r = (g >> 5) & 511, z = g >> 14;   // z uniform/block
    const int band = z & 7;
    if (threadIdx.x < 41)
        vrow[threadIdx.x] = mtf[band * 1681 + 20 * 41 + threadIdx.x] /
                            sqrtf(mtf[band * 1681 + 20 * 41 + 20]);
    __syncthreads();
    const float* row = outputs + (long)z * HWSZ + (long)r * IMG;
    // input cols 16q-20 .. 16q+35 (zero pad outside)
    float v[56];
#pragma unroll
    for (int f = 0; f < 14; ++f) {
        const int cb = 16 * q - 20 + 4 * f;
        if (cb >= 0 && cb + 3 < IMG) {
            const float4 t = *(const float4*)(row + cb);
            v[4 * f + 0] = t.x; v[4 * f + 1] = t.y;
            v[4 * f + 2] = t.z; v[4 * f + 3] = t.w;
        } else {
#pragma unroll
            for (int u = 0; u < 4; ++u) {
                const int cc = cb + u;
                v[4 * f + u] = (cc >= 0 && cc < IMG) ? row[cc] : 0.f;
            }
        }
    }
    float o[4] = {0.f, 0.f, 0.f, 0.f};
#pragma unroll
    for (int j = 0; j < 41; ++j) {
        const float w = vrow[j];
#pragma unroll
        for (int u = 0; u < 4; ++u) o[u] += w * v[2 + 4 * u + j];
    }
    float* dst = tmpS + ((long)z * IMG + r) * 128 + 4 * q;
    *(float4*)dst = make_float4(o[0], o[1], o[2], o[3]);
}

__global__ __launch_bounds__(256) void k_spec_v(const float* __restrict__ tmpS,
                                                const float* __restrict__ labels,
                                                const float* __restrict__ spec,
                                                const float* __restrict__ mtf,
                                                double* __restrict__ acc) {
    __shared__ double redT[4];
    __shared__ double redM[4];
    const int idx = blockIdx.x * 256 + threadIdx.x;
    const int cs = idx & 127, rs = (idx >> 7) & 127, z = idx >> 14;
    const int b = z >> 3, band = z & 7;
    __shared__ float ucol[41];
    if (threadIdx.x < 41)
        ucol[threadIdx.x] = mtf[band * 1681 + threadIdx.x * 41 + 20] /
                            sqrtf(mtf[band * 1681 + 20 * 41 + 20]);
    __syncthreads();
    const float* col = tmpS + (long)z * IMG * 128 + cs;
    float x = 0.f;
    const int rbase = 2 + 4 * rs - 20;
#pragma unroll
    for (int i = 0; i < 41; ++i) {
        int r = rbase + i;
        if (r >= 0 && r < IMG) x += ucol[i] * col[(long)r * 128];
    }
    const int gr = 2 + 4 * rs, gc = 2 + 4 * cs;
    float m = spec[(long)band * HWSZ + (long)gr * IMG + gc];
    float y = labels[((long)b * 9 + band) * HWSZ + (long)gr * IMG + gc];
    float t = fabsf(x * m - y * m);
    blockReduceAtomicAdd((double)t, acc + 0, redT);
    blockReduceAtomicAdd((double)m, acc + 1, redM);
}

__global__ void k_final(const double* __restrict__ acc, float* __restrict__ out) {
    double lspec = acc[0] / acc[1];
    double lstruct = acc[2] / (double)(NBATCH * NBANDS * HWSZ);
    out[0] = (float)(lspec + 0.25 * lstruct);
}

// ---------------------------------------------------------------------------
extern "C" void kernel_launch(void* const* d_in, const int* in_sizes, int n_in,
                              void* d_out, int out_size, void* d_ws, size_t ws_size,
                              hipStream_t stream) {
    const float* outputs = (const float*)d_in[0];   // (4,8,512,512)
    const float* labels  = (const float*)d_in[1];   // (4,9,512,512)
    const float* inp     = (const float*)d_in[2];   // (4,9,512,512)
    const float* mtf     = (const float*)d_in[3];   // (8,1,41,41)
    const float* spec    = (const float*)d_in[4];   // (1,8,512,512)
    float* out = (float*)d_out;

    const long IMGB = (long)HWSZ;     // one image in floats
    char* ws = (char*)d_ws;
    double* acc    = (double*)ws;                    // 4 doubles
    float* panf    = (float*)(ws + 1024);            // 4 imgs
    float* tmpH    = panf   + NBATCH * IMGB;         // 4 imgs
    float* da_pan8 = tmpH   + NBATCH * IMGB;         // 4 imgs
    float* saa8    = da_pan8 + NBATCH * IMGB;        // 4 imgs
    float* db_pan2 = saa8   + NBATCH * IMGB;         // 4 imgs
    float* sbb2    = db_pan2 + NBATCH * IMGB;        // 4 imgs
    float* tmpS    = sbb2   + NBATCH * IMGB;         // 8 imgs (4*8*512*128)
    float* bufA    = tmpS   + 8 * IMGB;              // 32 imgs
    float* bufB    = bufA   + 32 * IMGB;             // 32 imgs
    float* bufC    = bufB   + 32 * IMGB;             // 32 imgs
    float* bufD    = bufC   + 32 * IMGB;             // 32 imgs

    hipMemsetAsync(acc, 0, 4 * sizeof(double), stream);

    // --- per-batch shared fields -----------------------------------------
    k_pan_h<<<dim3(2, 512, NBATCH), 256, 0, stream>>>(inp, mtf, tmpH);
    k_pan_v<<<dim3(2, 512, NBATCH), 256, 0, stream>>>(tmpH, mtf, panf);
    k_da<8><<<dim3(16, 16, NBATCH), 256, 0, stream>>>(panf, (long)HWSZ, da_pan8);
    k_sq<8><<<dim3(16, 16, NBATCH), 256, 0, stream>>>(da_pan8, saa8);
    k_da<2><<<dim3(16, 16, NBATCH), 256, 0, stream>>>(labels + 8 * IMGB,
                                                      (long)9 * HWSZ, db_pan2);
    k_sq<2><<<dim3(16, 16, NBATCH), 256, 0, stream>>>(db_pan2, sbb2);

    // --- L_spec ----------------------------------------------------------
    k_spec_h<<<2048, 256, 0, stream>>>(outputs, mtf, tmpS);
    k_spec_v<<<dim3(2048), 256, 0, stream>>>(tmpS, labels, spec, mtf, acc);

    // --- w=8 pipeline: thr ------------------------------------------------
    kHbox<8><<<4096, 256, 0, stream>>>(inp, 9 * IMGB, IMGB, bufA);
    kVda<8><<<2048, 256, 0, stream>>>(bufA, inp, 9 * IMGB, IMGB, bufB);   // da_ms
    kHprod<8><<<4096, 256, 0, stream>>>(bufB, da_pan8, bufC, bufD);
    kVfin8<<<2048, 256, 0, stream>>>(bufC, bufD, saa8, bufA);             // thr

    // --- w=2 pipeline: X, Y reduce ---------------------------------------
    kHbox<2><<<4096, 256, 0, stream>>>(outputs, 8 * IMGB, IMGB, bufB);
    kVda<2><<<2048, 256, 0, stream>>>(bufB, outputs, 8 * IMGB, IMGB, bufC); // da_out
    kHprod<2><<<4096, 256, 0, stream>>>(bufC, db_pan2, bufB, bufD);
    kVfin2<<<2048, 256, 0, stream>>>(bufB, bufD, sbb2, bufA, acc);

    k_final<<<1, 1, 0, stream>>>(acc, out);
}

// Round 6
// 346.245 us; speedup vs baseline: 2.5737x; 1.1977x over previous
//
#include <hip/hip_runtime.h>
#include <hip/hip_bf16.h>

// Problem constants
#define HWSZ   262144   // 512*512
#define IMG    512
#define NBATCH 4
#define NBANDS 8

typedef _Float16 half_t;
typedef _Float16 half4v __attribute__((ext_vector_type(4)));
typedef _Float16 half8v __attribute__((ext_vector_type(8)));

// ---------------------------------------------------------------------------
// Block-level reduction: wave shuffle + LDS + one double atomic per block.
__device__ __forceinline__ void blockReduceAtomicAdd(double v, double* target,
                                                     double* red) {
    for (int off = 32; off > 0; off >>= 1) v += __shfl_down(v, off, 64);
    const int wave = threadIdx.x >> 6, lane = threadIdx.x & 63;
    if (lane == 0) red[wave] = v;
    __syncthreads();
    if (threadIdx.x == 0) atomicAdd(target, red[0] + red[1] + red[2] + red[3]);
}

// ---------------------------------------------------------------------------
// Pan smoothing (edge-pad 41x41 Gaussian, rank-1 factored), horizontal pass.
__global__ __launch_bounds__(256) void k_pan_h(const float* __restrict__ inp,
                                               const float* __restrict__ mtf,
                                               float* __restrict__ tmpH) {
    __shared__ float seg[296];
    __shared__ float vrow[41];
    const int tid = threadIdx.x;
    const int b = blockIdx.z, r = blockIdx.y, c0 = blockIdx.x * 256;
    if (tid < 41) vrow[tid] = mtf[20 * 41 + tid] / sqrtf(mtf[20 * 41 + 20]);
    const float* pan = inp + ((long)b * 9 + 8) * HWSZ + (long)r * IMG;
    for (int e = tid; e < 296; e += 256) {
        int c = c0 - 20 + e;
        c = min(max(c, 0), IMG - 1);
        seg[e] = pan[c];
    }
    __syncthreads();
    float s = 0.f;
#pragma unroll
    for (int j = 0; j < 41; ++j) s += vrow[j] * seg[tid + j];
    tmpH[(long)b * HWSZ + (long)r * IMG + c0 + tid] = s;
}

__global__ __launch_bounds__(256) void k_pan_v(const float* __restrict__ tmpH,
                                               const float* __restrict__ mtf,
                                               float* __restrict__ panf) {
    __shared__ float ucol[41];
    const int tid = threadIdx.x;
    const int b = blockIdx.z, r = blockIdx.y, c = blockIdx.x * 256 + tid;
    if (tid < 41) ucol[tid] = mtf[tid * 41 + 20] / sqrtf(mtf[20 * 41 + 20]);
    __syncthreads();
    const float* base = tmpH + (long)b * HWSZ;
    float s = 0.f;
#pragma unroll
    for (int i = 0; i < 41; ++i) {
        int rr = min(max(r - 20 + i, 0), IMG - 1);
        s += ucol[i] * base[(long)rr * IMG + c];
    }
    panf[(long)b * HWSZ + (long)r * IMG + c] = s;
}

// ---------------------------------------------------------------------------
// Small-field (4-image) helpers, LDS tile based (cheap at this size).
template <int W>
__global__ __launch_bounds__(256) void k_da(const float* __restrict__ in,
                                            long inBatchStride,
                                            float* __restrict__ out) {
    constexpr int TS = 32, WIN = 2 * W, NN = 4 * W * W, RE = TS + WIN - 1;
    constexpr int SR = RE;
    constexpr int ST = 33;
    __shared__ float RAW[RE * SR];
    __shared__ float T[RE * ST];
    const int tid = threadIdx.x;
    const int tr0 = blockIdx.y * TS, tc0 = blockIdx.x * TS;
    const float* src = in + (long)blockIdx.z * inBatchStride;
    for (int e = tid; e < RE * RE; e += 256) {
        int r = e / RE, c = e % RE;
        int gr = tr0 - (W - 1) + r, gc = tc0 - (W - 1) + c;
        float v = 0.f;
        if (gr >= 0 && gr < IMG && gc >= 0 && gc < IMG) v = src[(long)gr * IMG + gc];
        RAW[r * SR + c] = v;
    }
    __syncthreads();
    for (int e = tid; e < RE * TS; e += 256) {
        int r = e >> 5, j = e & 31;
        float s = 0.f;
#pragma unroll
        for (int k = 0; k < WIN; ++k) s += RAW[r * SR + j + k];
        T[r * ST + j] = s;
    }
    __syncthreads();
    float* dst = out + (long)blockIdx.z * HWSZ;
    for (int e = tid; e < TS * TS; e += 256) {
        int pr = e >> 5, pc = e & 31;
        float s = 0.f;
#pragma unroll
        for (int k = 0; k < WIN; ++k) s += T[(pr + k) * ST + pc];
        float da = RAW[(pr + W - 1) * SR + (pc + W - 1)] - s * (1.0f / NN);
        dst[(long)(tr0 + pr) * IMG + tc0 + pc] = da;
    }
}

template <int W>
__global__ __launch_bounds__(256) void k_sq(const float* __restrict__ in,
                                            float* __restrict__ out) {
    constexpr int TS = 32, WIN = 2 * W, RE = TS + WIN - 1;
    constexpr int SR = RE, ST = 33;
    __shared__ float RAW[RE * SR];
    __shared__ float T[RE * ST];
    const int tid = threadIdx.x;
    const int tr0 = blockIdx.y * TS, tc0 = blockIdx.x * TS;
    const float* src = in + (long)blockIdx.z * HWSZ;
    for (int e = tid; e < RE * RE; e += 256) {
        int r = e / RE, c = e % RE;
        int gr = tr0 - (W - 1) + r, gc = tc0 - (W - 1) + c;
        float v = 0.f;
        if (gr >= 0 && gr < IMG && gc >= 0 && gc < IMG) v = src[(long)gr * IMG + gc];
        RAW[r * SR + c] = v;
    }
    __syncthreads();
    for (int e = tid; e < RE * TS; e += 256) {
        int r = e >> 5, j = e & 31;
        float s = 0.f;
#pragma unroll
        for (int k = 0; k < WIN; ++k) {
            float v = RAW[r * SR + j + k];
            s += v * v;
        }
        T[r * ST + j] = s;
    }
    __syncthreads();
    float* dst = out + (long)blockIdx.z * HWSZ;
    for (int e = tid; e < TS * TS; e += 256) {
        int pr = e >> 5, pc = e & 31;
        float s = 0.f;
#pragma unroll
        for (int k = 0; k < WIN; ++k) s += T[(pr + k) * ST + pc];
        dst[(long)(tr0 + pr) * IMG + tc0 + pc] = s;
    }
}

// ---------------------------------------------------------------------------
// Full-size (32-image) separable box passes, zero LDS, register sliding.
// Intermediates stored as fp16 (t, da, pH1/pH2, thr) — error budget analysis:
// t is divided by n in the mean (err ~1e-5); da/product rel err ~5e-4 ->
// thr/X err ~2e-3, loss err ~1e-3 << 1.3e-2 threshold.
// H kernels: grid 4096 x 256; thread -> 8 consecutive outputs of one row.

template <int W> struct WinDims {
    static constexpr int A  = (W + 3) & ~3;
    static constexpr int NU = A + W + 8;              // elements actually used
    static constexpr int NF = (NU + 3) / 4;           // 4-elem chunks loaded
    static constexpr int NV = NF * 4;                 // padded array size
};

template <int W>
__device__ __forceinline__ void loadRowWin(const float* __restrict__ row, int c0,
                                           float* v) {
    constexpr int A = WinDims<W>::A;
    constexpr int NF = WinDims<W>::NF;
#pragma unroll
    for (int f = 0; f < NF; ++f) {
        const int cb = c0 - A + 4 * f;
        if (cb >= 0 && cb + 3 < IMG) {
            const float4 t = *(const float4*)(row + cb);
            v[4 * f + 0] = t.x; v[4 * f + 1] = t.y;
            v[4 * f + 2] = t.z; v[4 * f + 3] = t.w;
        } else {
#pragma unroll
            for (int u = 0; u < 4; ++u) {
                const int c = cb + u;
                v[4 * f + u] = (c >= 0 && c < IMG) ? row[c] : 0.f;
            }
        }
    }
}

template <int W>
__device__ __forceinline__ void loadRowWinH(const half_t* __restrict__ row, int c0,
                                            float* v) {
    constexpr int A = WinDims<W>::A;
    constexpr int NF = WinDims<W>::NF;
#pragma unroll
    for (int f = 0; f < NF; ++f) {
        const int cb = c0 - A + 4 * f;   // multiple of 4 -> 8B aligned
        if (cb >= 0 && cb + 3 < IMG) {
            const half4v t = *(const half4v*)(row + cb);
            v[4 * f + 0] = (float)t[0]; v[4 * f + 1] = (float)t[1];
            v[4 * f + 2] = (float)t[2]; v[4 * f + 3] = (float)t[3];
        } else {
#pragma unroll
            for (int u = 0; u < 4; ++u) {
                const int c = cb + u;
                v[4 * f + u] = (c >= 0 && c < IMG) ? (float)row[c] : 0.f;
            }
        }
    }
}

// H box of a raw fp32 input field -> t (half, z*HWSZ layout)
template <int W>
__global__ __launch_bounds__(256) void kHbox(const float* __restrict__ in,
                                             long sB, long sC,
                                             half_t* __restrict__ out) {
    constexpr int A = WinDims<W>::A;
    const int g = blockIdx.x * 256 + threadIdx.x;
    const int c0 = (g & 63) << 3, r = (g >> 6) & 511, z = g >> 15;
    const float* row = in + (long)(z >> 3) * sB + (long)(z & 7) * sC + (long)r * IMG;
    float v[WinDims<W>::NV];
    loadRowWin<W>(row, c0, v);
    float o[8];
    float s = 0.f;
#pragma unroll
    for (int i = A - W + 1; i <= A + W; ++i) s += v[i];
    o[0] = s;
#pragma unroll
    for (int j = 1; j < 8; ++j) {
        s += v[A + W + j] - v[A - W + j];
        o[j] = s;
    }
    half8v h;
#pragma unroll
    for (int j = 0; j < 8; ++j) h[j] = (half_t)o[j];
    *(half8v*)(out + (long)z * HWSZ + (long)r * IMG + c0) = h;   // 16B aligned
}

// V box of t (half) + epilogue da = orig - box/n (half out). grid 2048 x 256.
template <int W>
__global__ __launch_bounds__(256) void kVda(const half_t* __restrict__ t,
                                            const float* __restrict__ orig,
                                            long sB, long sC,
                                            half_t* __restrict__ out) {
    constexpr int NR = 2 * W + 15, NN = 4 * W * W;
    const int g = blockIdx.x * 256 + threadIdx.x;
    const int c = g & 511, rc = (g >> 9) & 31, z = g >> 14;
    const int r0 = rc * 16;
    const half_t* tz = t + (long)z * HWSZ + c;
    float v[NR];
#pragma unroll
    for (int i = 0; i < NR; ++i) {
        const int rr = r0 - W + 1 + i;
        v[i] = (rr >= 0 && rr < IMG) ? (float)tz[(long)rr * IMG] : 0.f;
    }
    const float* oz = orig + (long)(z >> 3) * sB + (long)(z & 7) * sC + c;
    half_t* dst = out + (long)z * HWSZ + c;
    float s = 0.f;
#pragma unroll
    for (int i = 0; i < 2 * W; ++i) s += v[i];
#pragma unroll
    for (int j = 0; j < 16; ++j) {
        dst[(long)(r0 + j) * IMG] =
            (half_t)(oz[(long)(r0 + j) * IMG] - s * (1.0f / NN));
        if (j < 15) s += v[2 * W + j] - v[j];
    }
}

// H box of (da*dshared) and (da*da). da half z*HWSZ; dshared fp32 (z>>3)*HWSZ.
template <int W>
__global__ __launch_bounds__(256) void kHprod(const half_t* __restrict__ da,
                                              const float* __restrict__ dsh,
                                              half_t* __restrict__ o1,
                                              half_t* __restrict__ o2) {
    constexpr int A = WinDims<W>::A;
    constexpr int NU = WinDims<W>::NU;
    constexpr int NV = WinDims<W>::NV;
    const int g = blockIdx.x * 256 + threadIdx.x;
    const int c0 = (g & 63) << 3, r = (g >> 6) & 511, z = g >> 15;
    const half_t* rowa = da + (long)z * HWSZ + (long)r * IMG;
    const float* rows = dsh + (long)(z >> 3) * HWSZ + (long)r * IMG;
    float va[NV], vs[NV];
    loadRowWinH<W>(rowa, c0, va);
    loadRowWin<W>(rows, c0, vs);
    float p1[NV], p2[NV];
#pragma unroll
    for (int i = 0; i < NU; ++i) { p1[i] = va[i] * vs[i]; p2[i] = va[i] * va[i]; }
    float a[8], b[8];
    float s1 = 0.f, s2 = 0.f;
#pragma unroll
    for (int i = A - W + 1; i <= A + W; ++i) { s1 += p1[i]; s2 += p2[i]; }
    a[0] = s1; b[0] = s2;
#pragma unroll
    for (int j = 1; j < 8; ++j) {
        s1 += p1[A + W + j] - p1[A - W + j];
        s2 += p2[A + W + j] - p2[A - W + j];
        a[j] = s1; b[j] = s2;
    }
    half8v h1, h2;
#pragma unroll
    for (int j = 0; j < 8; ++j) { h1[j] = (half_t)a[j]; h2[j] = (half_t)b[j]; }
    *(half8v*)(o1 + (long)z * HWSZ + (long)r * IMG + c0) = h1;
    *(half8v*)(o2 + (long)z * HWSZ + (long)r * IMG + c0) = h2;
}

// V box of pH1/pH2 (w=8) + epilogue thr = 1 - sab/(sqrt(saa*sbb)+eps)
__global__ __launch_bounds__(256) void kVfin8(const half_t* __restrict__ pH1,
                                              const half_t* __restrict__ pH2,
                                              const float* __restrict__ saa,
                                              half_t* __restrict__ thr) {
    constexpr int W = 8, NR = 2 * W + 15;
    const int g = blockIdx.x * 256 + threadIdx.x;
    const int c = g & 511, rc = (g >> 9) & 31, z = g >> 14;
    const int r0 = rc * 16, b = z >> 3;
    const half_t* t1 = pH1 + (long)z * HWSZ + c;
    const half_t* t2 = pH2 + (long)z * HWSZ + c;
    float v1[NR], v2[NR];
#pragma unroll
    for (int i = 0; i < NR; ++i) {
        const int rr = r0 - W + 1 + i;
        const bool ok = (rr >= 0 && rr < IMG);
        v1[i] = ok ? (float)t1[(long)rr * IMG] : 0.f;
        v2[i] = ok ? (float)t2[(long)rr * IMG] : 0.f;
    }
    const float* sz = saa + (long)b * HWSZ + c;
    half_t* dst = thr + (long)z * HWSZ + c;
    float s1 = 0.f, s2 = 0.f;
#pragma unroll
    for (int i = 0; i < 2 * W; ++i) { s1 += v1[i]; s2 += v2[i]; }
#pragma unroll
    for (int j = 0; j < 16; ++j) {
        const float sa = sz[(long)(r0 + j) * IMG];
        const float den = sqrtf(fmaxf(sa * s2, 0.f)) + 1e-20f;
        dst[(long)(r0 + j) * IMG] = (half_t)(1.0f - s1 / den);
        if (j < 15) {
            s1 += v1[2 * W + j] - v1[j];
            s2 += v2[2 * W + j] - v2[j];
        }
    }
}

// V box of qH1/qH2 (w=2) + epilogue: Xc, X, compare vs thr, reduce Y.
__global__ __launch_bounds__(256) void kVfin2(const half_t* __restrict__ qH1,
                                              const half_t* __restrict__ qH2,
                                              const float* __restrict__ sbb,
                                              const half_t* __restrict__ thr,
                                              double* __restrict__ acc) {
    constexpr int W = 2, NR = 2 * W + 15;
    __shared__ double red[4];
    const int g = blockIdx.x * 256 + threadIdx.x;
    const int c = g & 511, rc = (g >> 9) & 31, z = g >> 14;
    const int r0 = rc * 16, b = z >> 3;
    const half_t* t1 = qH1 + (long)z * HWSZ + c;
    const half_t* t2 = qH2 + (long)z * HWSZ + c;
    float v1[NR], v2[NR];
#pragma unroll
    for (int i = 0; i < NR; ++i) {
        const int rr = r0 - W + 1 + i;
        const bool ok = (rr >= 0 && rr < IMG);
        v1[i] = ok ? (float)t1[(long)rr * IMG] : 0.f;
        v2[i] = ok ? (float)t2[(long)rr * IMG] : 0.f;
    }
    const float* sz = sbb + (long)b * HWSZ + c;
    const half_t* tz = thr + (long)z * HWSZ + c;
    float s1 = 0.f, s2 = 0.f;
#pragma unroll
    for (int i = 0; i < 2 * W; ++i) { s1 += v1[i]; s2 += v2[i]; }
    double ysum = 0.0;
#pragma unroll
    for (int j = 0; j < 16; ++j) {
        const float sb = sz[(long)(r0 + j) * IMG];
        const float den = sqrtf(fmaxf(s2 * sb, 0.f)) + 1e-20f;
        const float Xc = s1 / den;
        const float X = 1.0f - fmaxf(Xc, -1.0f);
        const float th = (float)tz[(long)(r0 + j) * IMG];
        if (X > th) ysum += (double)X;
        if (j < 15) {
            s1 += v1[2 * W + j] - v1[j];
            s2 += v2[2 * W + j] - v2[j];
        }
    }
    blockReduceAtomicAdd(ysum, acc + 2, red);
}

// ---------------------------------------------------------------------------
// L_spec: strided MTF conv of outputs (rank-1 factored), H then V+reduce.
// H pass: 4 strided outputs/thread from 14 float4 register loads.
__global__ __launch_bounds__(256) void k_spec_h(const float* __restrict__ outputs,
                                                const float* __restrict__ mtf,
                                                float* __restrict__ tmpS) {
    __shared__ float vrow[41];
    const int g = blockIdx.x * 256 + threadIdx.x;
    const int q = g & 31, r = (g >> 5) & 511, z = g >> 14;   // z uniform/block
    const int band = z & 7;
    if (threadIdx.x < 41)
        vrow[threadIdx.x] = mtf[band * 1681 + 20 * 41 + threadIdx.x] /
                            sqrtf(mtf[band * 1681 + 20 * 41 + 20]);
    __syncthreads();
    const float* row = outputs + (long)z * HWSZ + (long)r * IMG;
    float v[56];
#pragma unroll
    for (int f = 0; f < 14; ++f) {
        const int cb = 16 * q - 20 + 4 * f;
        if (cb >= 0 && cb + 3 < IMG) {
            const float4 t = *(const float4*)(row + cb);
            v[4 * f + 0] = t.x; v[4 * f + 1] = t.y;
            v[4 * f + 2] = t.z; v[4 * f + 3] = t.w;
        } else {
#pragma unroll
            for (int u = 0; u < 4; ++u) {
                const int cc = cb + u;
                v[4 * f + u] = (cc >= 0 && cc < IMG) ? row[cc] : 0.f;
            }
        }
    }
    float o[4] = {0.f, 0.f, 0.f, 0.f};
#pragma unroll
    for (int j = 0; j < 41; ++j) {
        const float w = vrow[j];
#pragma unroll
        for (int u = 0; u < 4; ++u) o[u] += w * v[2 + 4 * u + j];
    }
    float* dst = tmpS + ((long)z * IMG + r) * 128 + 4 * q;
    *(float4*)dst = make_float4(o[0], o[1], o[2], o[3]);
}

// V pass: 4 outputs/thread along cs via float4 column loads; interior rows
// (rs in [5,122]) take a branch-free fully-unrolled path. grid 512 x 256.
__global__ __launch_bounds__(256) void k_spec_v(const float* __restrict__ tmpS,
                                                const float* __restrict__ labels,
                                                const float* __restrict__ spec,
                                                const float* __restrict__ mtf,
                                                double* __restrict__ acc) {
    __shared__ double redT[4];
    __shared__ double redM[4];
    __shared__ float ucol[41];
    const int g = blockIdx.x * 256 + threadIdx.x;
    const int q = g & 31, rs = (g >> 5) & 127, z = g >> 12;   // z uniform/block
    const int b = z >> 3, band = z & 7;
    if (threadIdx.x < 41)
        ucol[threadIdx.x] = mtf[band * 1681 + threadIdx.x * 41 + 20] /
                            sqrtf(mtf[band * 1681 + 20 * 41 + 20]);
    __syncthreads();
    const float* base = tmpS + (long)z * IMG * 128 + 4 * q;
    const int rbase = 4 * rs - 18;
    float o[4] = {0.f, 0.f, 0.f, 0.f};
    if (rbase >= 0 && rbase + 40 < IMG) {
#pragma unroll
        for (int i = 0; i < 41; ++i) {
            const float4 v = *(const float4*)(base + (long)(rbase + i) * 128);
            const float w = ucol[i];
            o[0] += w * v.x; o[1] += w * v.y; o[2] += w * v.z; o[3] += w * v.w;
        }
    } else {
        for (int i = 0; i < 41; ++i) {
            const int r = rbase + i;
            if (r >= 0 && r < IMG) {
                const float4 v = *(const float4*)(base + (long)r * 128);
                const float w = ucol[i];
                o[0] += w * v.x; o[1] += w * v.y; o[2] += w * v.z; o[3] += w * v.w;
            }
        }
    }
    const int gr = 2 + 4 * rs;
    float tsum = 0.f, msum = 0.f;
#pragma unroll
    for (int u = 0; u < 4; ++u) {
        const int gc = 2 + 4 * (4 * q + u);
        const float m = spec[(long)band * HWSZ + (long)gr * IMG + gc];
        const float y = labels[((long)b * 9 + band) * HWSZ + (long)gr * IMG + gc];
        tsum += fabsf(o[u] * m - y * m);
        msum += m;
    }
    blockReduceAtomicAdd((double)tsum, acc + 0, redT);
    blockReduceAtomicAdd((double)msum, acc + 1, redM);
}

__global__ void k_final(const double* __restrict__ acc, float* __restrict__ out) {
    double lspec = acc[0] / acc[1];
    double lstruct = acc[2] / (double)(NBATCH * NBANDS * HWSZ);
    out[0] = (float)(lspec + 0.25 * lstruct);
}

// ---------------------------------------------------------------------------
extern "C" void kernel_launch(void* const* d_in, const int* in_sizes, int n_in,
                              void* d_out, int out_size, void* d_ws, size_t ws_size,
                              hipStream_t stream) {
    const float* outputs = (const float*)d_in[0];   // (4,8,512,512)
    const float* labels  = (const float*)d_in[1];   // (4,9,512,512)
    const float* inp     = (const float*)d_in[2];   // (4,9,512,512)
    const float* mtf     = (const float*)d_in[3];   // (8,1,41,41)
    const float* spec    = (const float*)d_in[4];   // (1,8,512,512)
    float* out = (float*)d_out;

    const long IMGB = (long)HWSZ;     // one image in elements
    char* ws = (char*)d_ws;
    double* acc    = (double*)ws;                    // 4 doubles
    float* panf    = (float*)(ws + 1024);            // 4 imgs fp32
    float* tmpH    = panf   + NBATCH * IMGB;         // 4 imgs
    float* da_pan8 = tmpH   + NBATCH * IMGB;         // 4 imgs
    float* saa8    = da_pan8 + NBATCH * IMGB;        // 4 imgs
    float* db_pan2 = saa8   + NBATCH * IMGB;         // 4 imgs
    float* sbb2    = db_pan2 + NBATCH * IMGB;        // 4 imgs
    float* tmpS    = sbb2   + NBATCH * IMGB;         // 8 imgs fp32
    half_t* hT     = (half_t*)(tmpS + 8 * IMGB);     // 32 imgs half
    half_t* hDA    = hT  + 32 * IMGB;                // 32 imgs half
    half_t* hP1    = hDA + 32 * IMGB;                // 32 imgs half
    half_t* hP2    = hP1 + 32 * IMGB;                // 32 imgs half
    half_t* hTHR   = hP2 + 32 * IMGB;                // 32 imgs half

    hipMemsetAsync(acc, 0, 4 * sizeof(double), stream);

    // --- per-batch shared fields (fp32) ----------------------------------
    k_pan_h<<<dim3(2, 512, NBATCH), 256, 0, stream>>>(inp, mtf, tmpH);
    k_pan_v<<<dim3(2, 512, NBATCH), 256, 0, stream>>>(tmpH, mtf, panf);
    k_da<8><<<dim3(16, 16, NBATCH), 256, 0, stream>>>(panf, (long)HWSZ, da_pan8);
    k_sq<8><<<dim3(16, 16, NBATCH), 256, 0, stream>>>(da_pan8, saa8);
    k_da<2><<<dim3(16, 16, NBATCH), 256, 0, stream>>>(labels + 8 * IMGB,
                                                      (long)9 * HWSZ, db_pan2);
    k_sq<2><<<dim3(16, 16, NBATCH), 256, 0, stream>>>(db_pan2, sbb2);

    // --- L_spec ----------------------------------------------------------
    k_spec_h<<<2048, 256, 0, stream>>>(outputs, mtf, tmpS);
    k_spec_v<<<512, 256, 0, stream>>>(tmpS, labels, spec, mtf, acc);

    // --- w=8 pipeline: thr (half intermediates) --------------------------
    kHbox<8><<<4096, 256, 0, stream>>>(inp, 9 * IMGB, IMGB, hT);
    kVda<8><<<2048, 256, 0, stream>>>(hT, inp, 9 * IMGB, IMGB, hDA);   // da_ms
    kHprod<8><<<4096, 256, 0, stream>>>(hDA, da_pan8, hP1, hP2);
    kVfin8<<<2048, 256, 0, stream>>>(hP1, hP2, saa8, hTHR);            // thr

    // --- w=2 pipeline: X, Y reduce ---------------------------------------
    kHbox<2><<<4096, 256, 0, stream>>>(outputs, 8 * IMGB, IMGB, hT);
    kVda<2><<<2048, 256, 0, stream>>>(hT, outputs, 8 * IMGB, IMGB, hDA); // da_out
    kHprod<2><<<4096, 256, 0, stream>>>(hDA, db_pan2, hP1, hP2);
    kVfin2<<<2048, 256, 0, stream>>>(hP1, hP2, sbb2, hTHR, acc);

    k_final<<<1, 1, 0, stream>>>(acc, out);
}

// Round 7
// 322.487 us; speedup vs baseline: 2.7633x; 1.0737x over previous
//
#include <hip/hip_runtime.h>
#include <hip/hip_bf16.h>

// Problem constants
#define HWSZ   262144   // 512*512
#define IMG    512
#define NBATCH 4
#define NBANDS 8

typedef _Float16 half_t;
typedef _Float16 half2v __attribute__((ext_vector_type(2)));
typedef _Float16 half4v __attribute__((ext_vector_type(4)));
typedef _Float16 half8v __attribute__((ext_vector_type(8)));

// ---------------------------------------------------------------------------
// Block-level reduction: wave shuffle + LDS + one double atomic per block.
__device__ __forceinline__ void blockReduceAtomicAdd(double v, double* target,
                                                     double* red) {
    for (int off = 32; off > 0; off >>= 1) v += __shfl_down(v, off, 64);
    const int wave = threadIdx.x >> 6, lane = threadIdx.x & 63;
    if (lane == 0) red[wave] = v;
    __syncthreads();
    if (threadIdx.x == 0) atomicAdd(target, red[0] + red[1] + red[2] + red[3]);
}

// ---------------------------------------------------------------------------
// Pan smoothing (edge-pad 41x41 Gaussian, rank-1 factored), horizontal pass.
__global__ __launch_bounds__(256) void k_pan_h(const float* __restrict__ inp,
                                               const float* __restrict__ mtf,
                                               float* __restrict__ tmpH) {
    __shared__ float seg[296];
    __shared__ float vrow[41];
    const int tid = threadIdx.x;
    const int b = blockIdx.z, r = blockIdx.y, c0 = blockIdx.x * 256;
    if (tid < 41) vrow[tid] = mtf[20 * 41 + tid] / sqrtf(mtf[20 * 41 + 20]);
    const float* pan = inp + ((long)b * 9 + 8) * HWSZ + (long)r * IMG;
    for (int e = tid; e < 296; e += 256) {
        int c = c0 - 20 + e;
        c = min(max(c, 0), IMG - 1);
        seg[e] = pan[c];
    }
    __syncthreads();
    float s = 0.f;
#pragma unroll
    for (int j = 0; j < 41; ++j) s += vrow[j] * seg[tid + j];
    tmpH[(long)b * HWSZ + (long)r * IMG + c0 + tid] = s;
}

__global__ __launch_bounds__(256) void k_pan_v(const float* __restrict__ tmpH,
                                               const float* __restrict__ mtf,
                                               float* __restrict__ panf) {
    __shared__ float ucol[41];
    const int tid = threadIdx.x;
    const int b = blockIdx.z, r = blockIdx.y, c = blockIdx.x * 256 + tid;
    if (tid < 41) ucol[tid] = mtf[tid * 41 + 20] / sqrtf(mtf[20 * 41 + 20]);
    __syncthreads();
    const float* base = tmpH + (long)b * HWSZ;
    float s = 0.f;
#pragma unroll
    for (int i = 0; i < 41; ++i) {
        int rr = min(max(r - 20 + i, 0), IMG - 1);
        s += ucol[i] * base[(long)rr * IMG + c];
    }
    panf[(long)b * HWSZ + (long)r * IMG + c] = s;
}

// ---------------------------------------------------------------------------
// Small-field (4-image) helpers, LDS tile based (cheap at this size).
template <int W>
__global__ __launch_bounds__(256) void k_da(const float* __restrict__ in,
                                            long inBatchStride,
                                            float* __restrict__ out) {
    constexpr int TS = 32, WIN = 2 * W, NN = 4 * W * W, RE = TS + WIN - 1;
    constexpr int SR = RE;
    constexpr int ST = 33;
    __shared__ float RAW[RE * SR];
    __shared__ float T[RE * ST];
    const int tid = threadIdx.x;
    const int tr0 = blockIdx.y * TS, tc0 = blockIdx.x * TS;
    const float* src = in + (long)blockIdx.z * inBatchStride;
    for (int e = tid; e < RE * RE; e += 256) {
        int r = e / RE, c = e % RE;
        int gr = tr0 - (W - 1) + r, gc = tc0 - (W - 1) + c;
        float v = 0.f;
        if (gr >= 0 && gr < IMG && gc >= 0 && gc < IMG) v = src[(long)gr * IMG + gc];
        RAW[r * SR + c] = v;
    }
    __syncthreads();
    for (int e = tid; e < RE * TS; e += 256) {
        int r = e >> 5, j = e & 31;
        float s = 0.f;
#pragma unroll
        for (int k = 0; k < WIN; ++k) s += RAW[r * SR + j + k];
        T[r * ST + j] = s;
    }
    __syncthreads();
    float* dst = out + (long)blockIdx.z * HWSZ;
    for (int e = tid; e < TS * TS; e += 256) {
        int pr = e >> 5, pc = e & 31;
        float s = 0.f;
#pragma unroll
        for (int k = 0; k < WIN; ++k) s += T[(pr + k) * ST + pc];
        float da = RAW[(pr + W - 1) * SR + (pc + W - 1)] - s * (1.0f / NN);
        dst[(long)(tr0 + pr) * IMG + tc0 + pc] = da;
    }
}

template <int W>
__global__ __launch_bounds__(256) void k_sq(const float* __restrict__ in,
                                            float* __restrict__ out) {
    constexpr int TS = 32, WIN = 2 * W, RE = TS + WIN - 1;
    constexpr int SR = RE, ST = 33;
    __shared__ float RAW[RE * SR];
    __shared__ float T[RE * ST];
    const int tid = threadIdx.x;
    const int tr0 = blockIdx.y * TS, tc0 = blockIdx.x * TS;
    const float* src = in + (long)blockIdx.z * HWSZ;
    for (int e = tid; e < RE * RE; e += 256) {
        int r = e / RE, c = e % RE;
        int gr = tr0 - (W - 1) + r, gc = tc0 - (W - 1) + c;
        float v = 0.f;
        if (gr >= 0 && gr < IMG && gc >= 0 && gc < IMG) v = src[(long)gr * IMG + gc];
        RAW[r * SR + c] = v;
    }
    __syncthreads();
    for (int e = tid; e < RE * TS; e += 256) {
        int r = e >> 5, j = e & 31;
        float s = 0.f;
#pragma unroll
        for (int k = 0; k < WIN; ++k) {
            float v = RAW[r * SR + j + k];
            s += v * v;
        }
        T[r * ST + j] = s;
    }
    __syncthreads();
    float* dst = out + (long)blockIdx.z * HWSZ;
    for (int e = tid; e < TS * TS; e += 256) {
        int pr = e >> 5, pc = e & 31;
        float s = 0.f;
#pragma unroll
        for (int k = 0; k < WIN; ++k) s += T[(pr + k) * ST + pc];
        dst[(long)(tr0 + pr) * IMG + tc0 + pc] = s;
    }
}

// ---------------------------------------------------------------------------
// Full-size (32-image) separable box passes, zero LDS, register sliding.
// Intermediates fp16 (t, da, products). Error budget: thr/X err ~2e-3,
// loss err ~1e-3 << 1.3e-2 threshold (measured absmax 0.0 at fp16).

template <int W> struct WinDims {
    static constexpr int A  = (W + 3) & ~3;
    static constexpr int NU = A + W + 8;              // elements actually used
    static constexpr int NF = (NU + 3) / 4;           // 4-elem chunks loaded
    static constexpr int NV = NF * 4;                 // padded array size
};

template <int W>
__device__ __forceinline__ void loadRowWin(const float* __restrict__ row, int c0,
                                           float* v) {
    constexpr int A = WinDims<W>::A;
    constexpr int NF = WinDims<W>::NF;
#pragma unroll
    for (int f = 0; f < NF; ++f) {
        const int cb = c0 - A + 4 * f;
        if (cb >= 0 && cb + 3 < IMG) {
            const float4 t = *(const float4*)(row + cb);
            v[4 * f + 0] = t.x; v[4 * f + 1] = t.y;
            v[4 * f + 2] = t.z; v[4 * f + 3] = t.w;
        } else {
#pragma unroll
            for (int u = 0; u < 4; ++u) {
                const int c = cb + u;
                v[4 * f + u] = (c >= 0 && c < IMG) ? row[c] : 0.f;
            }
        }
    }
}

template <int W>
__device__ __forceinline__ void loadRowWinH(const half_t* __restrict__ row, int c0,
                                            float* v) {
    constexpr int A = WinDims<W>::A;
    constexpr int NF = WinDims<W>::NF;
#pragma unroll
    for (int f = 0; f < NF; ++f) {
        const int cb = c0 - A + 4 * f;   // multiple of 4 -> 8B aligned
        if (cb >= 0 && cb + 3 < IMG) {
            const half4v t = *(const half4v*)(row + cb);
            v[4 * f + 0] = (float)t[0]; v[4 * f + 1] = (float)t[1];
            v[4 * f + 2] = (float)t[2]; v[4 * f + 3] = (float)t[3];
        } else {
#pragma unroll
            for (int u = 0; u < 4; ++u) {
                const int c = cb + u;
                v[4 * f + u] = (c >= 0 && c < IMG) ? (float)row[c] : 0.f;
            }
        }
    }
}

// H box of a raw fp32 input field -> t (half, z*HWSZ layout). grid 4096 x 256.
template <int W>
__global__ __launch_bounds__(256) void kHbox(const float* __restrict__ in,
                                             long sB, long sC,
                                             half_t* __restrict__ out) {
    constexpr int A = WinDims<W>::A;
    const int g = blockIdx.x * 256 + threadIdx.x;
    const int c0 = (g & 63) << 3, r = (g >> 6) & 511, z = g >> 15;
    const float* row = in + (long)(z >> 3) * sB + (long)(z & 7) * sC + (long)r * IMG;
    float v[WinDims<W>::NV];
    loadRowWin<W>(row, c0, v);
    float o[8];
    float s = 0.f;
#pragma unroll
    for (int i = A - W + 1; i <= A + W; ++i) s += v[i];
    o[0] = s;
#pragma unroll
    for (int j = 1; j < 8; ++j) {
        s += v[A + W + j] - v[A - W + j];
        o[j] = s;
    }
    half8v h;
#pragma unroll
    for (int j = 0; j < 8; ++j) h[j] = (half_t)o[j];
    *(half8v*)(out + (long)z * HWSZ + (long)r * IMG + c0) = h;   // 16B aligned
}

// V box of t (half) + epilogue da = orig - box/n (half out).
// 2 columns/thread via half2/float2 loads. grid 1024 x 256.
template <int W>
__global__ __launch_bounds__(256) void kVda(const half_t* __restrict__ t,
                                            const float* __restrict__ orig,
                                            long sB, long sC,
                                            half_t* __restrict__ out) {
    constexpr int NR = 2 * W + 15, NN = 4 * W * W;
    const int g = blockIdx.x * 256 + threadIdx.x;
    const int cp = (g & 255) * 2;          // even column pair base
    const int rc = (g >> 8) & 31, z = g >> 13;
    const int r0 = rc * 16;
    const half_t* tz = t + (long)z * HWSZ + cp;
    float vx[NR], vy[NR];
#pragma unroll
    for (int i = 0; i < NR; ++i) {
        const int rr = r0 - W + 1 + i;
        if (rr >= 0 && rr < IMG) {
            const half2v h = *(const half2v*)(tz + (long)rr * IMG);
            vx[i] = (float)h[0]; vy[i] = (float)h[1];
        } else { vx[i] = 0.f; vy[i] = 0.f; }
    }
    const float* oz = orig + (long)(z >> 3) * sB + (long)(z & 7) * sC + cp;
    half_t* dst = out + (long)z * HWSZ + cp;
    float sx = 0.f, sy = 0.f;
#pragma unroll
    for (int i = 0; i < 2 * W; ++i) { sx += vx[i]; sy += vy[i]; }
#pragma unroll
    for (int j = 0; j < 16; ++j) {
        const float2 o = *(const float2*)(oz + (long)(r0 + j) * IMG);
        half2v h;
        h[0] = (half_t)(o.x - sx * (1.0f / NN));
        h[1] = (half_t)(o.y - sy * (1.0f / NN));
        *(half2v*)(dst + (long)(r0 + j) * IMG) = h;
        if (j < 15) {
            sx += vx[2 * W + j] - vx[j];
            sy += vy[2 * W + j] - vy[j];
        }
    }
}

// H box of (da*dshared) and (da*da). da half z*HWSZ; dshared fp32 (z>>3)*HWSZ.
template <int W>
__global__ __launch_bounds__(256) void kHprod(const half_t* __restrict__ da,
                                              const float* __restrict__ dsh,
                                              half_t* __restrict__ o1,
                                              half_t* __restrict__ o2) {
    constexpr int A = WinDims<W>::A;
    constexpr int NU = WinDims<W>::NU;
    constexpr int NV = WinDims<W>::NV;
    const int g = blockIdx.x * 256 + threadIdx.x;
    const int c0 = (g & 63) << 3, r = (g >> 6) & 511, z = g >> 15;
    const half_t* rowa = da + (long)z * HWSZ + (long)r * IMG;
    const float* rows = dsh + (long)(z >> 3) * HWSZ + (long)r * IMG;
    float va[NV], vs[NV];
    loadRowWinH<W>(rowa, c0, va);
    loadRowWin<W>(rows, c0, vs);
    float p1[NV], p2[NV];
#pragma unroll
    for (int i = 0; i < NU; ++i) { p1[i] = va[i] * vs[i]; p2[i] = va[i] * va[i]; }
    float a[8], b[8];
    float s1 = 0.f, s2 = 0.f;
#pragma unroll
    for (int i = A - W + 1; i <= A + W; ++i) { s1 += p1[i]; s2 += p2[i]; }
    a[0] = s1; b[0] = s2;
#pragma unroll
    for (int j = 1; j < 8; ++j) {
        s1 += p1[A + W + j] - p1[A - W + j];
        s2 += p2[A + W + j] - p2[A - W + j];
        a[j] = s1; b[j] = s2;
    }
    half8v h1, h2;
#pragma unroll
    for (int j = 0; j < 8; ++j) { h1[j] = (half_t)a[j]; h2[j] = (half_t)b[j]; }
    *(half8v*)(o1 + (long)z * HWSZ + (long)r * IMG + c0) = h1;
    *(half8v*)(o2 + (long)z * HWSZ + (long)r * IMG + c0) = h2;
}

// Fused V-final: w=8 V-box -> thr in registers, then w=2 V-box -> X, reduce Y.
// Same (c, r0, z) mapping as the old kVfin8/kVfin2. grid 2048 x 256.
__global__ __launch_bounds__(256) void kVfinBoth(const half_t* __restrict__ p1,
                                                 const half_t* __restrict__ p2,
                                                 const float* __restrict__ saa,
                                                 const half_t* __restrict__ q1,
                                                 const half_t* __restrict__ q2,
                                                 const float* __restrict__ sbb,
                                                 double* __restrict__ acc) {
    __shared__ double red[4];
    const int g = blockIdx.x * 256 + threadIdx.x;
    const int c = g & 511, rc = (g >> 9) & 31, z = g >> 14;
    const int r0 = rc * 16, b = z >> 3;
    const long zoff = (long)z * HWSZ + c, boff = (long)b * HWSZ + c;

    float thrv[16];
    {   // ---- w=8 phase: thr = 1 - sab/(sqrt(saa*sbb)+eps)
        constexpr int W = 8, NR = 2 * W + 15;
        const half_t* t1 = p1 + zoff;
        const half_t* t2 = p2 + zoff;
        float v1[NR], v2[NR];
#pragma unroll
        for (int i = 0; i < NR; ++i) {
            const int rr = r0 - W + 1 + i;
            const bool ok = (rr >= 0 && rr < IMG);
            v1[i] = ok ? (float)t1[(long)rr * IMG] : 0.f;
            v2[i] = ok ? (float)t2[(long)rr * IMG] : 0.f;
        }
        const float* sz = saa + boff;
        float s1 = 0.f, s2 = 0.f;
#pragma unroll
        for (int i = 0; i < 2 * W; ++i) { s1 += v1[i]; s2 += v2[i]; }
#pragma unroll
        for (int j = 0; j < 16; ++j) {
            const float sa = sz[(long)(r0 + j) * IMG];
            const float den = sqrtf(fmaxf(sa * s2, 0.f)) + 1e-20f;
            thrv[j] = 1.0f - s1 / den;
            if (j < 15) {
                s1 += v1[2 * W + j] - v1[j];
                s2 += v2[2 * W + j] - v2[j];
            }
        }
    }
    double ysum = 0.0;
    {   // ---- w=2 phase: X vs thr, accumulate Y
        constexpr int W = 2, NR = 2 * W + 15;
        const half_t* t1 = q1 + zoff;
        const half_t* t2 = q2 + zoff;
        float v1[NR], v2[NR];
#pragma unroll
        for (int i = 0; i < NR; ++i) {
            const int rr = r0 - W + 1 + i;
            const bool ok = (rr >= 0 && rr < IMG);
            v1[i] = ok ? (float)t1[(long)rr * IMG] : 0.f;
            v2[i] = ok ? (float)t2[(long)rr * IMG] : 0.f;
        }
        const float* sz = sbb + boff;
        float s1 = 0.f, s2 = 0.f;
#pragma unroll
        for (int i = 0; i < 2 * W; ++i) { s1 += v1[i]; s2 += v2[i]; }
#pragma unroll
        for (int j = 0; j < 16; ++j) {
            const float sb = sz[(long)(r0 + j) * IMG];
            const float den = sqrtf(fmaxf(s2 * sb, 0.f)) + 1e-20f;
            const float Xc = s1 / den;
            const float X = 1.0f - fmaxf(Xc, -1.0f);
            if (X > thrv[j]) ysum += (double)X;
            if (j < 15) {
                s1 += v1[2 * W + j] - v1[j];
                s2 += v2[2 * W + j] - v2[j];
            }
        }
    }
    blockReduceAtomicAdd(ysum, acc + 2, red);
}

// ---------------------------------------------------------------------------
// L_spec: strided MTF conv of outputs (rank-1 factored), H then V+reduce.
__global__ __launch_bounds__(256) void k_spec_h(const float* __restrict__ outputs,
                                                const float* __restrict__ mtf,
                                                float* __restrict__ tmpS) {
    __shared__ float vrow[41];
    const int g = blockIdx.x * 256 + threadIdx.x;
    const int q = g & 31, r = (g >> 5) & 511, z = g >> 14;   // z uniform/block
    const int band = z & 7;
    if (threadIdx.x < 41)
        vrow[threadIdx.x] = mtf[band * 1681 + 20 * 41 + threadIdx.x] /
                            sqrtf(mtf[band * 1681 + 20 * 41 + 20]);
    __syncthreads();
    const float* row = outputs + (long)z * HWSZ + (long)r * IMG;
    float v[56];
#pragma unroll
    for (int f = 0; f < 14; ++f) {
        const int cb = 16 * q - 20 + 4 * f;
        if (cb >= 0 && cb + 3 < IMG) {
            const float4 t = *(const float4*)(row + cb);
            v[4 * f + 0] = t.x; v[4 * f + 1] = t.y;
            v[4 * f + 2] = t.z; v[4 * f + 3] = t.w;
        } else {
#pragma unroll
            for (int u = 0; u < 4; ++u) {
                const int cc = cb + u;
                v[4 * f + u] = (cc >= 0 && cc < IMG) ? row[cc] : 0.f;
            }
        }
    }
    float o[4] = {0.f, 0.f, 0.f, 0.f};
#pragma unroll
    for (int j = 0; j < 41; ++j) {
        const float w = vrow[j];
#pragma unroll
        for (int u = 0; u < 4; ++u) o[u] += w * v[2 + 4 * u + j];
    }
    float* dst = tmpS + ((long)z * IMG + r) * 128 + 4 * q;
    *(float4*)dst = make_float4(o[0], o[1], o[2], o[3]);
}

__global__ __launch_bounds__(256) void k_spec_v(const float* __restrict__ tmpS,
                                                const float* __restrict__ labels,
                                                const float* __restrict__ spec,
                                                const float* __restrict__ mtf,
                                                double* __restrict__ acc) {
    __shared__ double redT[4];
    __shared__ double redM[4];
    __shared__ float ucol[41];
    const int g = blockIdx.x * 256 + threadIdx.x;
    const int q = g & 31, rs = (g >> 5) & 127, z = g >> 12;   // z uniform/block
    const int b = z >> 3, band = z & 7;
    if (threadIdx.x < 41)
        ucol[threadIdx.x] = mtf[band * 1681 + threadIdx.x * 41 + 20] /
                            sqrtf(mtf[band * 1681 + 20 * 41 + 20]);
    __syncthreads();
    const float* base = tmpS + (long)z * IMG * 128 + 4 * q;
    const int rbase = 4 * rs - 18;
    float o[4] = {0.f, 0.f, 0.f, 0.f};
    if (rbase >= 0 && rbase + 40 < IMG) {
#pragma unroll
        for (int i = 0; i < 41; ++i) {
            const float4 v = *(const float4*)(base + (long)(rbase + i) * 128);
            const float w = ucol[i];
            o[0] += w * v.x; o[1] += w * v.y; o[2] += w * v.z; o[3] += w * v.w;
        }
    } else {
        for (int i = 0; i < 41; ++i) {
            const int r = rbase + i;
            if (r >= 0 && r < IMG) {
                const float4 v = *(const float4*)(base + (long)r * 128);
                const float w = ucol[i];
                o[0] += w * v.x; o[1] += w * v.y; o[2] += w * v.z; o[3] += w * v.w;
            }
        }
    }
    const int gr = 2 + 4 * rs;
    float tsum = 0.f, msum = 0.f;
#pragma unroll
    for (int u = 0; u < 4; ++u) {
        const int gc = 2 + 4 * (4 * q + u);
        const float m = spec[(long)band * HWSZ + (long)gr * IMG + gc];
        const float y = labels[((long)b * 9 + band) * HWSZ + (long)gr * IMG + gc];
        tsum += fabsf(o[u] * m - y * m);
        msum += m;
    }
    blockReduceAtomicAdd((double)tsum, acc + 0, redT);
    blockReduceAtomicAdd((double)msum, acc + 1, redM);
}

__global__ void k_final(const double* __restrict__ acc, float* __restrict__ out) {
    double lspec = acc[0] / acc[1];
    double lstruct = acc[2] / (double)(NBATCH * NBANDS * HWSZ);
    out[0] = (float)(lspec + 0.25 * lstruct);
}

// ---------------------------------------------------------------------------
extern "C" void kernel_launch(void* const* d_in, const int* in_sizes, int n_in,
                              void* d_out, int out_size, void* d_ws, size_t ws_size,
                              hipStream_t stream) {
    const float* outputs = (const float*)d_in[0];   // (4,8,512,512)
    const float* labels  = (const float*)d_in[1];   // (4,9,512,512)
    const float* inp     = (const float*)d_in[2];   // (4,9,512,512)
    const float* mtf     = (const float*)d_in[3];   // (8,1,41,41)
    const float* spec    = (const float*)d_in[4];   // (1,8,512,512)
    float* out = (float*)d_out;

    const long IMGB = (long)HWSZ;     // one image in elements
    char* ws = (char*)d_ws;
    double* acc    = (double*)ws;                    // 4 doubles
    float* panf    = (float*)(ws + 1024);            // 4 imgs fp32
    float* tmpH    = panf   + NBATCH * IMGB;         // 4 imgs
    float* da_pan8 = tmpH   + NBATCH * IMGB;         // 4 imgs
    float* saa8    = da_pan8 + NBATCH * IMGB;        // 4 imgs
    float* db_pan2 = saa8   + NBATCH * IMGB;         // 4 imgs
    float* sbb2    = db_pan2 + NBATCH * IMGB;        // 4 imgs
    float* tmpS    = sbb2   + NBATCH * IMGB;         // 8 imgs fp32
    half_t* hT     = (half_t*)(tmpS + 8 * IMGB);     // 32 imgs half (scratch)
    half_t* hDA    = hT  + 32 * IMGB;                // 32 imgs half (scratch)
    half_t* hP1    = hDA + 32 * IMGB;                // 32 imgs half (w=8 prod)
    half_t* hP2    = hP1 + 32 * IMGB;                // 32 imgs half
    half_t* hQ1    = hP2 + 32 * IMGB;                // 32 imgs half (w=2 prod)
    half_t* hQ2    = hQ1 + 32 * IMGB;                // 32 imgs half

    hipMemsetAsync(acc, 0, 4 * sizeof(double), stream);

    // --- per-batch shared fields (fp32) ----------------------------------
    k_pan_h<<<dim3(2, 512, NBATCH), 256, 0, stream>>>(inp, mtf, tmpH);
    k_pan_v<<<dim3(2, 512, NBATCH), 256, 0, stream>>>(tmpH, mtf, panf);
    k_da<8><<<dim3(16, 16, NBATCH), 256, 0, stream>>>(panf, (long)HWSZ, da_pan8);
    k_sq<8><<<dim3(16, 16, NBATCH), 256, 0, stream>>>(da_pan8, saa8);
    k_da<2><<<dim3(16, 16, NBATCH), 256, 0, stream>>>(labels + 8 * IMGB,
                                                      (long)9 * HWSZ, db_pan2);
    k_sq<2><<<dim3(16, 16, NBATCH), 256, 0, stream>>>(db_pan2, sbb2);

    // --- L_spec ----------------------------------------------------------
    k_spec_h<<<2048, 256, 0, stream>>>(outputs, mtf, tmpS);
    k_spec_v<<<512, 256, 0, stream>>>(tmpS, labels, spec, mtf, acc);

    // --- w=8 pipeline: products ------------------------------------------
    kHbox<8><<<4096, 256, 0, stream>>>(inp, 9 * IMGB, IMGB, hT);
    kVda<8><<<1024, 256, 0, stream>>>(hT, inp, 9 * IMGB, IMGB, hDA);   // da_ms
    kHprod<8><<<4096, 256, 0, stream>>>(hDA, da_pan8, hP1, hP2);

    // --- w=2 pipeline: products ------------------------------------------
    kHbox<2><<<4096, 256, 0, stream>>>(outputs, 8 * IMGB, IMGB, hT);
    kVda<2><<<1024, 256, 0, stream>>>(hT, outputs, 8 * IMGB, IMGB, hDA); // da_out
    kHprod<2><<<4096, 256, 0, stream>>>(hDA, db_pan2, hQ1, hQ2);

    // --- fused V-final: thr in registers, X, Y reduce --------------------
    kVfinBoth<<<2048, 256, 0, stream>>>(hP1, hP2, saa8, hQ1, hQ2, sbb2, acc);

    k_final<<<1, 1, 0, stream>>>(acc, out);
}